// Round 7
// baseline (705.545 us; speedup 1.0000x reference)
//
#include <hip/hip_runtime.h>
#include <hip/hip_bf16.h>

typedef unsigned short u16;
typedef unsigned int u32;
typedef __bf16 bf16_t;
typedef bf16_t bf16x8 __attribute__((ext_vector_type(8)));
typedef float fx4 __attribute__((ext_vector_type(4)));

#define TT 2048
#define HH 8
#define KK 64
#define VV 192
#define CC 1536
#define SPLITS 8
#define JBLK (TT / SPLITS)

__device__ __forceinline__ float bf2f(u16 b) {
  union { u32 u; float f; } v; v.u = ((u32)b) << 16; return v.f;
}
__device__ __forceinline__ u16 f2bf(float f) {
  union { float f; u32 u; } v; v.f = f;
  return (u16)((v.u + 0x7FFFu + ((v.u >> 16) & 1u)) >> 16);
}
__device__ __forceinline__ fx4 mfma16(bf16x8 a, bf16x8 b, fx4 c) {
  return __builtin_amdgcn_mfma_f32_16x16x32_bf16(a, b, c, 0, 0, 0);
}

// ---------------- prep: 4 weight transposes (f32->bf16) + cidx table ---------
__global__ __launch_bounds__(256) void prep_kernel(
    const float* __restrict__ Wq, const float* __restrict__ Wk,
    const float* __restrict__ Wv, const float* __restrict__ Wo,
    u16* __restrict__ WqT, u16* __restrict__ WkT,
    u16* __restrict__ WvT, u16* __restrict__ WoT,
    unsigned char* __restrict__ cidx_g) {
  const int z = blockIdx.z;
  const int t = threadIdx.x;
  if (z == 4) {
    if (blockIdx.x != 0 || blockIdx.y != 0) return;
    float pr = expf(logf((float)(TT + 1)) / 16.0f);
    float cw[16];
    float wv = pr;
    for (int i = 0; i < 16; ++i) { cw[i] = wv - 1.0f; wv *= pr; }
    for (int idx = t; idx < TT; idx += 256) {
      int c = 15;
      for (int i = 14; i >= 0; --i)
        if (cw[i] > (float)idx) c = i;
      cidx_g[idx] = (unsigned char)c;
    }
    return;
  }
  if (z < 2 && blockIdx.x >= 8) return;
  const float* in = (z == 0) ? Wq : (z == 1) ? Wk : (z == 2) ? Wv : Wo;
  u16* out = (z == 0) ? WqT : (z == 1) ? WkT : (z == 2) ? WvT : WoT;
  const int in_rs = (z < 2) ? 512 : 1536;
  const int out_rs = 1536;

  __shared__ u16 tile[64][68];
  const int c0 = blockIdx.x * 64, r0 = blockIdx.y * 64;
  for (int i = 0; i < 4; ++i) {
    int idx = i * 256 + t;
    int r = idx >> 4, ch = idx & 15;
    float4 fv = *(const float4*)&in[(size_t)(r0 + r) * in_rs + c0 + ch * 4];
    tile[r][ch * 4 + 0] = f2bf(fv.x);
    tile[r][ch * 4 + 1] = f2bf(fv.y);
    tile[r][ch * 4 + 2] = f2bf(fv.z);
    tile[r][ch * 4 + 3] = f2bf(fv.w);
  }
  __syncthreads();
  for (int i = 0; i < 4; ++i) {
    int idx = i * 256 + t;
    int r = idx >> 4, ch = idx & 15;
    u16 a0 = tile[ch * 4 + 0][r], a1 = tile[ch * 4 + 1][r];
    u16 a2 = tile[ch * 4 + 2][r], a3 = tile[ch * 4 + 3][r];
    uint2 d;
    d.x = (u32)a0 | ((u32)a1 << 16);
    d.y = (u32)a2 | ((u32)a3 << 16);
    *(uint2*)&out[(size_t)(c0 + r) * out_rs + r0 + ch * 4] = d;
  }
}

// ---------------- x f32 -> bf16 elementwise ----------------------------------
__global__ __launch_bounds__(256) void xconv_kernel(const float* __restrict__ x,
                                                    u16* __restrict__ xbf) {
  size_t i = ((size_t)blockIdx.x * 256 + threadIdx.x) * 8;
  float4 f0 = *(const float4*)&x[i];
  float4 f1 = *(const float4*)&x[i + 4];
  union { u16 h[8]; uint4 v; } pk;
  pk.h[0] = f2bf(f0.x); pk.h[1] = f2bf(f0.y);
  pk.h[2] = f2bf(f0.z); pk.h[3] = f2bf(f0.w);
  pk.h[4] = f2bf(f1.x); pk.h[5] = f2bf(f1.y);
  pk.h[6] = f2bf(f1.z); pk.h[7] = f2bf(f1.w);
  *(uint4*)&xbf[i] = pk.v;
}

// ---------------- unified QKV projection GEMM --------------------------------
// A = xbf [2048,1536] bf16; grid (20,16): cb<4 -> Q, cb<8 -> K, else V.
__global__ __launch_bounds__(256) void gemm_qkv(
    const u16* __restrict__ xbf, const u16* __restrict__ WqT,
    const u16* __restrict__ WkT, const u16* __restrict__ WvT,
    u16* __restrict__ qw, u16* __restrict__ qr, u16* __restrict__ Kws,
    u16* __restrict__ vtmp, const float* __restrict__ rwb,
    const float* __restrict__ rrb) {
  __shared__ u16 As[128 * 32];
  __shared__ u16 Bs[128 * 32];
  const int cb = blockIdx.x;
  const u16* BT = (cb < 4) ? WqT : (cb < 8) ? WkT : WvT;
  const int n0 = ((cb < 4) ? cb : (cb < 8) ? cb - 4 : cb - 8) * 128;
  const int t = threadIdx.x;
  const int lane = t & 63, wid = t >> 6;
  const int l16 = lane & 15, quad = lane >> 4;
  const int wm = wid >> 1, wn = wid & 1;
  const int m0 = blockIdx.y * 128;

  fx4 acc[4][4] = {};
  for (int k0 = 0; k0 < CC; k0 += 32) {
    __syncthreads();
    for (int i = 0; i < 2; ++i) {
      int idx = (i * 256 + t) * 8;
      int r = idx >> 5, ko = idx & 31;
      *(uint4*)&As[r * 32 + ko] = *(const uint4*)&xbf[(size_t)(m0 + r) * CC + k0 + ko];
      *(uint4*)&Bs[r * 32 + ko] = *(const uint4*)&BT[(size_t)(n0 + r) * CC + k0 + ko];
    }
    __syncthreads();
    bf16x8 af[4], bfr[4];
    for (int mi = 0; mi < 4; ++mi)
      af[mi] = *(const bf16x8*)&As[(wm * 64 + mi * 16 + l16) * 32 + quad * 8];
    for (int ni = 0; ni < 4; ++ni)
      bfr[ni] = *(const bf16x8*)&Bs[(wn * 64 + ni * 16 + l16) * 32 + quad * 8];
    for (int mi = 0; mi < 4; ++mi)
      for (int ni = 0; ni < 4; ++ni)
        acc[mi][ni] = mfma16(af[mi], bfr[ni], acc[mi][ni]);
  }

  for (int mi = 0; mi < 4; ++mi)
    for (int ni = 0; ni < 4; ++ni)
      for (int r = 0; r < 4; ++r) {
        int row = m0 + wm * 64 + mi * 16 + quad * 4 + r;
        int col = n0 + wn * 64 + ni * 16 + l16;
        float v = acc[mi][ni][r];
        if (cb < 8) {
          int h = col >> 6, kx = col & 63;
          size_t o = ((size_t)h * TT + row) * 64 + kx;
          if (cb < 4) {
            float qs = v * 0.125f;
            qw[o] = f2bf(qs + rwb[col]);
            qr[o] = f2bf(qs + rrb[col]);
          } else {
            Kws[o] = f2bf(v);
          }
        } else {
          vtmp[(size_t)row * CC + col] = f2bf(v);
        }
      }
}

// ---------------- bf16 MFMA GEMM (out-proj): FLOAT out = A@BT^T + bias -------
__global__ __launch_bounds__(256) void gemm_out(
    const u16* __restrict__ A, const u16* __restrict__ BT,
    float* __restrict__ out0, const float* __restrict__ bias0) {
  __shared__ u16 As[128 * 32];
  __shared__ u16 Bs[128 * 32];
  const int t = threadIdx.x;
  const int lane = t & 63, wid = t >> 6;
  const int l16 = lane & 15, quad = lane >> 4;
  const int wm = wid >> 1, wn = wid & 1;
  const int m0 = blockIdx.y * 128, n0 = blockIdx.x * 128;

  fx4 acc[4][4] = {};
  for (int k0 = 0; k0 < CC; k0 += 32) {
    __syncthreads();
    for (int i = 0; i < 2; ++i) {
      int idx = (i * 256 + t) * 8;
      int r = idx >> 5, ko = idx & 31;
      *(uint4*)&As[r * 32 + ko] = *(const uint4*)&A[(size_t)(m0 + r) * CC + k0 + ko];
      *(uint4*)&Bs[r * 32 + ko] = *(const uint4*)&BT[(size_t)(n0 + r) * CC + k0 + ko];
    }
    __syncthreads();
    bf16x8 af[4], bfr[4];
    for (int mi = 0; mi < 4; ++mi)
      af[mi] = *(const bf16x8*)&As[(wm * 64 + mi * 16 + l16) * 32 + quad * 8];
    for (int ni = 0; ni < 4; ++ni)
      bfr[ni] = *(const bf16x8*)&Bs[(wn * 64 + ni * 16 + l16) * 32 + quad * 8];
    for (int mi = 0; mi < 4; ++mi)
      for (int ni = 0; ni < 4; ++ni)
        acc[mi][ni] = mfma16(af[mi], bfr[ni], acc[mi][ni]);
  }
  for (int mi = 0; mi < 4; ++mi)
    for (int ni = 0; ni < 4; ++ni)
      for (int r = 0; r < 4; ++r) {
        int row = m0 + wm * 64 + mi * 16 + quad * 4 + r;
        int col = n0 + wn * 64 + ni * 16 + l16;
        out0[(size_t)row * CC + col] = acc[mi][ni][r] + bias0[col];
      }
}

// ---------------- U/W suffix-sum tables --------------------------------------
__global__ __launch_bounds__(256) void uw_kernel(
    const u16* __restrict__ qr, const float* __restrict__ Wr,
    float* __restrict__ U, float* __restrict__ W) {
  const int h = blockIdx.y;
  const int t = threadIdx.x;
  const int ty = t >> 5, i = t & 31;
  const int q = blockIdx.x * 8 + ty;
  const u16* qp = qr + ((size_t)h * TT + q) * 64;
  const float* wp = Wr + (size_t)i * (HH * KK) + h * 64;
  float s = 0.0f;
  for (int kx = 0; kx < 64; ++kx) s += bf2f(qp[kx]) * wp[kx];
  __shared__ float u[8][33];
  u[ty][i] = s;
  __syncthreads();
  if (i < 16) {
    float su = 0.f, sw = 0.f;
    for (int j = i; j < 16; ++j) { su += u[ty][j]; sw += u[ty][16 + j]; }
    U[((size_t)h * TT + q) * 16 + i] = su;
    W[((size_t)h * TT + q) * 16 + i] = sw;
  }
}

// ---------------- split-K flash attention, S^T layout ------------------------
// 1D grid 2048; h=blk&7 (XCD pin), ks=(blk>>3)&7, q0=(blk>>6)*64.
// S^T = K·Q^T: per-lane softmax over 16 j-registers (q = l16), 2+2 bpermutes.
// Batched K (8) and V (12/chunk) register loads to keep L2 latency pipelined.
__global__ __launch_bounds__(256, 3) void attn_split(
    const u16* __restrict__ qw, const u16* __restrict__ Kw,
    const u16* __restrict__ vT, const float* __restrict__ Ug,
    const float* __restrict__ Wg, const unsigned char* __restrict__ cidx_g,
    u16* __restrict__ o_part, float* __restrict__ m_part,
    float* __restrict__ l_part) {
  const int blk = blockIdx.x;
  const int h = blk & 7;
  const int ks = (blk >> 3) & 7;
  const int q0 = (blk >> 6) * 64;
  const int t = threadIdx.x;
  const int lane = t & 63, w = t >> 6;
  const int l16 = lane & 15, quad = lane >> 4;

  __shared__ unsigned char cidx[TT];   // 2048 B
  __shared__ float2 UW[64][17];        // 8704 B (pad 17 -> distinct banks per l16)
  __shared__ u16 Pl[4][16 * 72];       // 9216 B

  *(uint2*)&cidx[t * 8] = *(const uint2*)&cidx_g[t * 8];
  for (int i = t; i < 64 * 16; i += 256) {
    int ql = i >> 4, c = i & 15;
    UW[ql][c] = make_float2(Ug[((size_t)h * TT + q0 + ql) * 16 + c],
                            Wg[((size_t)h * TT + q0 + ql) * 16 + c]);
  }
  __syncthreads();

  const int qloc = w * 16 + l16;       // this lane's q (softmax dim)
  const int q_abs = q0 + qloc;
  const u16* qp = qw + ((size_t)h * TT + q_abs) * 64 + quad * 8;
  const bf16x8 aq0 = *(const bf16x8*)qp;
  const bf16x8 aq1 = *(const bf16x8*)(qp + 32);

  float m_s = -3.0e38f, l_s = 0.0f;
  fx4 o[12] = {};
  const u16* kbase = Kw + (size_t)h * TT * 64;
  const u16* vbase = vT + (size_t)h * VV * TT;

  for (int j0 = ks * JBLK; j0 < (ks + 1) * JBLK; j0 += 64) {
    // batched K-fragment loads (8 x b128)
    bf16x8 kf[8];
    for (int jt = 0; jt < 4; ++jt) {
      const u16* kp = kbase + (size_t)(j0 + jt * 16 + l16) * 64 + quad * 8;
      kf[jt * 2] = *(const bf16x8*)kp;
      kf[jt * 2 + 1] = *(const bf16x8*)(kp + 32);
    }
    // S^T: rows j (quad*4+r), cols q (l16)
    fx4 s[4];
    for (int jt = 0; jt < 4; ++jt) {
      fx4 z = {0.f, 0.f, 0.f, 0.f};
      z = mfma16(kf[jt * 2], aq0, z);
      s[jt] = mfma16(kf[jt * 2 + 1], aq1, z);
    }
    // rel term: batched category + UW lookups (q fixed per lane)
    const int dbase = j0 + quad * 4 - q_abs;
    int cc[16];
    for (int jt = 0; jt < 4; ++jt)
      for (int r = 0; r < 4; ++r) {
        int d = dbase + jt * 16 + r;
        cc[jt * 4 + r] = cidx[d < 0 ? -d : d];
      }
    float2 uwv[16];
    for (int i = 0; i < 16; ++i) uwv[i] = UW[qloc][cc[i]];
    for (int jt = 0; jt < 4; ++jt)
      for (int r = 0; r < 4; ++r) {
        int d = dbase + jt * 16 + r;
        float2 z = uwv[jt * 4 + r];
        s[jt][r] += z.x + (d > 0 ? z.y : (d < 0 ? -z.y : 0.0f));
      }
    // per-lane online softmax over 16 regs + 2-step quad reduction
    float mx = s[0][0];
    for (int jt = 0; jt < 4; ++jt)
      for (int r = 0; r < 4; ++r) mx = fmaxf(mx, s[jt][r]);
    mx = fmaxf(mx, __shfl_xor(mx, 16, 64));
    mx = fmaxf(mx, __shfl_xor(mx, 32, 64));
    float mnew = fmaxf(m_s, mx);
    float alpha = __expf(m_s - mnew);
    float p16[16];
    float ps = 0.0f;
    for (int jt = 0; jt < 4; ++jt)
      for (int r = 0; r < 4; ++r) {
        float p = __expf(s[jt][r] - mnew);
        p16[jt * 4 + r] = p;
        ps += p;
      }
    ps += __shfl_xor(ps, 16, 64);
    ps += __shfl_xor(ps, 32, 64);
    l_s = l_s * alpha + ps;
    m_s = mnew;
    // rescale o (rows q = quad*4+r) by alpha of that q
    float a4[4];
    for (int r = 0; r < 4; ++r) a4[r] = __shfl(alpha, quad * 4 + r, 16);
    for (int vt = 0; vt < 12; ++vt)
      for (int r = 0; r < 4; ++r) o[vt][r] *= a4[r];
    // batched V chunk-0 loads (overlap with P LDS round trip)
    bf16x8 bv[12];
    for (int vt = 0; vt < 12; ++vt)
      bv[vt] = *(const bf16x8*)(vbase + (size_t)(vt * 16 + l16) * TT + j0 + quad * 8);
    // P -> LDS (4 consecutive j = r pack into b64); wave-private region
    asm volatile("s_waitcnt lgkmcnt(0)" ::: "memory");
    for (int jt = 0; jt < 4; ++jt) {
      union { u16 h4[4]; uint2 v; } pk;
      for (int r = 0; r < 4; ++r) pk.h4[r] = f2bf(p16[jt * 4 + r]);
      *(uint2*)&Pl[w][l16 * 72 + jt * 16 + quad * 4] = pk.v;
    }
    asm volatile("s_waitcnt lgkmcnt(0)" ::: "memory");
    bf16x8 pf0 = *(const bf16x8*)&Pl[w][l16 * 72 + quad * 8];
    bf16x8 pf1 = *(const bf16x8*)&Pl[w][l16 * 72 + 32 + quad * 8];
    // PV chunk 0
    for (int vt = 0; vt < 12; ++vt) o[vt] = mfma16(pf0, bv[vt], o[vt]);
    // batched V chunk-1 loads + PV chunk 1
    for (int vt = 0; vt < 12; ++vt)
      bv[vt] = *(const bf16x8*)(vbase + (size_t)(vt * 16 + l16) * TT + j0 + 32 + quad * 8);
    for (int vt = 0; vt < 12; ++vt) o[vt] = mfma16(pf1, bv[vt], o[vt]);
  }

  // unnormalized partials; o rows are q = quad*4+r, cols v = vt*16+l16
  for (int r = 0; r < 4; ++r) {
    int row = q0 + w * 16 + quad * 4 + r;
    size_t base = ((size_t)(ks * HH + h) * TT + row) * VV;
    for (int vt = 0; vt < 12; ++vt) o_part[base + vt * 16 + l16] = f2bf(o[vt][r]);
  }
  if (quad == 0) {
    m_part[(size_t)(ks * HH + h) * TT + q_abs] = m_s;
    l_part[(size_t)(ks * HH + h) * TT + q_abs] = l_s;
  }
}

// ---------------- combine split-K partials -> bf16 aout ----------------------
__global__ __launch_bounds__(256) void attn_combine(
    const u16* __restrict__ o_part, const float* __restrict__ m_part,
    const float* __restrict__ l_part, u16* __restrict__ aout) {
  const int h = blockIdx.y;
  const int row = blockIdx.x * 16 + (threadIdx.x >> 4);
  const int c0 = (threadIdx.x & 15) * 12;

  float m[SPLITS], M = -3.0e38f;
  for (int s = 0; s < SPLITS; ++s) {
    m[s] = m_part[(size_t)(s * HH + h) * TT + row];
    M = fmaxf(M, m[s]);
  }
  float lsum = 0.0f, wgt[SPLITS];
  for (int s = 0; s < SPLITS; ++s) {
    wgt[s] = __expf(m[s] - M);
    lsum += wgt[s] * l_part[(size_t)(s * HH + h) * TT + row];
  }
  float o[12];
  for (int j = 0; j < 12; ++j) o[j] = 0.0f;
  for (int s = 0; s < SPLITS; ++s) {
    const u16* op = o_part + ((size_t)(s * HH + h) * TT + row) * VV + c0;
    float wgts = wgt[s];
    uint2 u0 = *(const uint2*)&op[0];
    uint2 u1 = *(const uint2*)&op[4];
    uint2 u2 = *(const uint2*)&op[8];
    u32 uu[6] = {u0.x, u0.y, u1.x, u1.y, u2.x, u2.y};
    for (int j = 0; j < 6; ++j) {
      o[j * 2 + 0] = fmaf(wgts, bf2f((u16)(uu[j] & 0xFFFF)), o[j * 2 + 0]);
      o[j * 2 + 1] = fmaf(wgts, bf2f((u16)(uu[j] >> 16)), o[j * 2 + 1]);
    }
  }
  float inv = 1.0f / lsum;
  union { u16 hx[12]; uint2 v2[3]; } pk;
  for (int j = 0; j < 12; ++j) pk.hx[j] = f2bf(o[j] * inv);
  u16* dst = aout + (size_t)row * CC + h * VV + c0;
  *(uint2*)&dst[0] = pk.v2[0];
  *(uint2*)&dst[4] = pk.v2[1];
  *(uint2*)&dst[8] = pk.v2[2];
}

// ---------------- bf16 transpose for v ---------------------------------------
__global__ __launch_bounds__(256) void transpose_bf16(
    const u16* __restrict__ in, u16* __restrict__ out,
    int in_rs, int out_rs, long in_bs, long out_bs) {
  __shared__ u16 tile[64][68];
  const int t = threadIdx.x;
  const int c0 = blockIdx.x * 64, r0 = blockIdx.y * 64;
  const u16* inp = in + (size_t)blockIdx.z * in_bs;
  u16* outp = out + (size_t)blockIdx.z * out_bs;
  for (int i = 0; i < 4; ++i) {
    int idx = i * 256 + t;
    int r = idx >> 4, ch = idx & 15;
    *(uint2*)&tile[r][ch * 4] =
        *(const uint2*)&inp[(size_t)(r0 + r) * in_rs + c0 + ch * 4];
  }
  __syncthreads();
  for (int i = 0; i < 4; ++i) {
    int idx = i * 256 + t;
    int r = idx >> 4, ch = idx & 15;
    u16 a0 = tile[ch * 4 + 0][r], a1 = tile[ch * 4 + 1][r];
    u16 a2 = tile[ch * 4 + 2][r], a3 = tile[ch * 4 + 3][r];
    uint2 d;
    d.x = (u32)a0 | ((u32)a1 << 16);
    d.y = (u32)a2 | ((u32)a3 << 16);
    *(uint2*)&outp[(size_t)(c0 + r) * out_rs + r0 + ch * 4] = d;
  }
}

extern "C" void kernel_launch(void* const* d_in, const int* in_sizes, int n_in,
                              void* d_out, int out_size, void* d_ws, size_t ws_size,
                              hipStream_t stream) {
  (void)in_sizes; (void)n_in; (void)out_size; (void)ws_size;
  const float* x   = (const float*)d_in[0];
  const float* Wq  = (const float*)d_in[1];
  const float* Wk  = (const float*)d_in[2];
  const float* Wv  = (const float*)d_in[3];
  const float* Wr  = (const float*)d_in[4];
  const float* rwb = (const float*)d_in[5];
  const float* rrb = (const float*)d_in[6];
  const float* Wo  = (const float*)d_in[7];
  const float* bo  = (const float*)d_in[8];

  char* ws = (char*)d_ws;
  size_t off = 0;
  auto alloc = [&](size_t bytes) -> void* {
    void* p = ws + off;
    off += (bytes + 255) & ~(size_t)255;
    return p;
  };
  u16* WqT  = (u16*)alloc((size_t)512 * 1536 * 2);
  u16* WkT  = (u16*)alloc((size_t)512 * 1536 * 2);
  u16* WvT  = (u16*)alloc((size_t)1536 * 1536 * 2);
  u16* WoT  = (u16*)alloc((size_t)1536 * 1536 * 2);
  u16* xbf  = (u16*)alloc((size_t)TT * CC * 2);
  u16* qw   = (u16*)alloc((size_t)HH * TT * 64 * 2);
  u16* qr   = (u16*)alloc((size_t)HH * TT * 64 * 2);
  u16* Kws  = (u16*)alloc((size_t)HH * TT * 64 * 2);
  u16* vtmp = (u16*)alloc((size_t)TT * CC * 2);
  u16* vTw  = (u16*)alloc((size_t)HH * VV * TT * 2);
  float* Uw = (float*)alloc((size_t)HH * TT * 16 * 4);
  float* Ww = (float*)alloc((size_t)HH * TT * 16 * 4);
  u16* aout = (u16*)alloc((size_t)TT * CC * 2);
  unsigned char* cidx_g = (unsigned char*)alloc(TT);
  u16* o_part   = (u16*)alloc((size_t)SPLITS * HH * TT * VV * 2);
  float* m_part = (float*)alloc((size_t)SPLITS * HH * TT * 4);
  float* l_part = (float*)alloc((size_t)SPLITS * HH * TT * 4);

  prep_kernel<<<dim3(24, 24, 5), 256, 0, stream>>>(Wq, Wk, Wv, Wo,
                                                   WqT, WkT, WvT, WoT, cidx_g);
  xconv_kernel<<<dim3(1536), 256, 0, stream>>>(x, xbf);

  gemm_qkv<<<dim3(20, 16), 256, 0, stream>>>(xbf, WqT, WkT, WvT,
                                             qw, qr, Kws, vtmp, rwb, rrb);

  transpose_bf16<<<dim3(3, 32, 8), 256, 0, stream>>>(vtmp, vTw, 1536, 2048, 192, (long)192 * 2048);
  uw_kernel<<<dim3(256, 8), 256, 0, stream>>>(qr, Wr, Uw, Ww);

  attn_split<<<dim3(2048), 256, 0, stream>>>(qw, Kws, vTw, Uw, Ww, cidx_g,
                                             o_part, m_part, l_part);
  attn_combine<<<dim3(128, 8), 256, 0, stream>>>(o_part, m_part, l_part, aout);

  gemm_out<<<dim3(12, 16), 256, 0, stream>>>(aout, WoT, (float*)d_out, bo);
}

// Round 8
// 369.210 us; speedup vs baseline: 1.9110x; 1.9110x over previous
//
#include <hip/hip_runtime.h>
#include <hip/hip_bf16.h>

typedef unsigned short u16;
typedef unsigned int u32;
typedef __bf16 bf16_t;
typedef bf16_t bf16x8 __attribute__((ext_vector_type(8)));
typedef float fx4 __attribute__((ext_vector_type(4)));

#define TT 2048
#define HH 8
#define KK 64
#define VV 192
#define CC 1536
#define SPLITS 8
#define JBLK (TT / SPLITS)

__device__ __forceinline__ float bf2f(u16 b) {
  union { u32 u; float f; } v; v.u = ((u32)b) << 16; return v.f;
}
__device__ __forceinline__ u16 f2bf(float f) {
  union { float f; u32 u; } v; v.f = f;
  return (u16)((v.u + 0x7FFFu + ((v.u >> 16) & 1u)) >> 16);
}
__device__ __forceinline__ fx4 mfma16(bf16x8 a, bf16x8 b, fx4 c) {
  return __builtin_amdgcn_mfma_f32_16x16x32_bf16(a, b, c, 0, 0, 0);
}

// ---------------- prep: 4 weight transposes (f32->bf16) + cidx table ---------
__global__ __launch_bounds__(256) void prep_kernel(
    const float* __restrict__ Wq, const float* __restrict__ Wk,
    const float* __restrict__ Wv, const float* __restrict__ Wo,
    u16* __restrict__ WqT, u16* __restrict__ WkT,
    u16* __restrict__ WvT, u16* __restrict__ WoT,
    unsigned char* __restrict__ cidx_g) {
  const int z = blockIdx.z;
  const int t = threadIdx.x;
  if (z == 4) {
    if (blockIdx.x != 0 || blockIdx.y != 0) return;
    float pr = expf(logf((float)(TT + 1)) / 16.0f);
    float cw[16];
    float wv = pr;
    for (int i = 0; i < 16; ++i) { cw[i] = wv - 1.0f; wv *= pr; }
    for (int idx = t; idx < TT; idx += 256) {
      int c = 15;
      for (int i = 14; i >= 0; --i)
        if (cw[i] > (float)idx) c = i;
      cidx_g[idx] = (unsigned char)c;
    }
    return;
  }
  if (z < 2 && blockIdx.x >= 8) return;
  const float* in = (z == 0) ? Wq : (z == 1) ? Wk : (z == 2) ? Wv : Wo;
  u16* out = (z == 0) ? WqT : (z == 1) ? WkT : (z == 2) ? WvT : WoT;
  const int in_rs = (z < 2) ? 512 : 1536;
  const int out_rs = 1536;

  __shared__ u16 tile[64][68];
  const int c0 = blockIdx.x * 64, r0 = blockIdx.y * 64;
#pragma unroll
  for (int i = 0; i < 4; ++i) {
    int idx = i * 256 + t;
    int r = idx >> 4, ch = idx & 15;
    float4 fv = *(const float4*)&in[(size_t)(r0 + r) * in_rs + c0 + ch * 4];
    tile[r][ch * 4 + 0] = f2bf(fv.x);
    tile[r][ch * 4 + 1] = f2bf(fv.y);
    tile[r][ch * 4 + 2] = f2bf(fv.z);
    tile[r][ch * 4 + 3] = f2bf(fv.w);
  }
  __syncthreads();
#pragma unroll
  for (int i = 0; i < 4; ++i) {
    int idx = i * 256 + t;
    int r = idx >> 4, ch = idx & 15;
    u16 a0 = tile[ch * 4 + 0][r], a1 = tile[ch * 4 + 1][r];
    u16 a2 = tile[ch * 4 + 2][r], a3 = tile[ch * 4 + 3][r];
    uint2 d;
    d.x = (u32)a0 | ((u32)a1 << 16);
    d.y = (u32)a2 | ((u32)a3 << 16);
    *(uint2*)&out[(size_t)(c0 + r) * out_rs + r0 + ch * 4] = d;
  }
}

// ---------------- x f32 -> bf16 elementwise ----------------------------------
__global__ __launch_bounds__(256) void xconv_kernel(const float* __restrict__ x,
                                                    u16* __restrict__ xbf) {
  size_t i = ((size_t)blockIdx.x * 256 + threadIdx.x) * 8;
  float4 f0 = *(const float4*)&x[i];
  float4 f1 = *(const float4*)&x[i + 4];
  union { u16 h[8]; uint4 v; } pk;
  pk.h[0] = f2bf(f0.x); pk.h[1] = f2bf(f0.y);
  pk.h[2] = f2bf(f0.z); pk.h[3] = f2bf(f0.w);
  pk.h[4] = f2bf(f1.x); pk.h[5] = f2bf(f1.y);
  pk.h[6] = f2bf(f1.z); pk.h[7] = f2bf(f1.w);
  *(uint4*)&xbf[i] = pk.v;
}

// ---------------- merged Q+K projection GEMM (bf16 A) ------------------------
// grid (8,16): bx<4 -> Q epilogue (scale+both biases), else K epilogue.
__global__ __launch_bounds__(256) void gemm_qk(
    const u16* __restrict__ xbf, const u16* __restrict__ WqT,
    const u16* __restrict__ WkT, u16* __restrict__ qw, u16* __restrict__ qr,
    u16* __restrict__ Kws, const float* __restrict__ rwb,
    const float* __restrict__ rrb) {
  __shared__ u16 As[128 * 32];
  __shared__ u16 Bs[128 * 32];
  const bool isq = blockIdx.x < 4;
  const u16* BT = isq ? WqT : WkT;
  const int t = threadIdx.x;
  const int lane = t & 63, wid = t >> 6;
  const int l16 = lane & 15, quad = lane >> 4;
  const int wm = wid >> 1, wn = wid & 1;
  const int m0 = blockIdx.y * 128, n0 = (blockIdx.x & 3) * 128;

  fx4 acc[4][4] = {};
  for (int k0 = 0; k0 < CC; k0 += 32) {
    __syncthreads();
#pragma unroll
    for (int i = 0; i < 2; ++i) {
      int idx = (i * 256 + t) * 8;
      int r = idx >> 5, ko = idx & 31;
      *(uint4*)&As[r * 32 + ko] = *(const uint4*)&xbf[(size_t)(m0 + r) * CC + k0 + ko];
      *(uint4*)&Bs[r * 32 + ko] = *(const uint4*)&BT[(size_t)(n0 + r) * CC + k0 + ko];
    }
    __syncthreads();
    bf16x8 af[4], bfr[4];
#pragma unroll
    for (int mi = 0; mi < 4; ++mi)
      af[mi] = *(const bf16x8*)&As[(wm * 64 + mi * 16 + l16) * 32 + quad * 8];
#pragma unroll
    for (int ni = 0; ni < 4; ++ni)
      bfr[ni] = *(const bf16x8*)&Bs[(wn * 64 + ni * 16 + l16) * 32 + quad * 8];
#pragma unroll
    for (int mi = 0; mi < 4; ++mi)
#pragma unroll
      for (int ni = 0; ni < 4; ++ni)
        acc[mi][ni] = mfma16(af[mi], bfr[ni], acc[mi][ni]);
  }

#pragma unroll
  for (int mi = 0; mi < 4; ++mi)
#pragma unroll
    for (int ni = 0; ni < 4; ++ni)
#pragma unroll
      for (int r = 0; r < 4; ++r) {
        int row = m0 + wm * 64 + mi * 16 + quad * 4 + r;
        int col = n0 + wn * 64 + ni * 16 + l16;
        float v = acc[mi][ni][r];
        int h = col >> 6, kx = col & 63;
        size_t o = ((size_t)h * TT + row) * 64 + kx;
        if (isq) {
          float qs = v * 0.125f;
          qw[o] = f2bf(qs + rwb[col]);
          qr[o] = f2bf(qs + rrb[col]);
        } else {
          Kws[o] = f2bf(v);
        }
      }
}

// ---------------- V projection GEMM (bf16 A): vtmp = xbf @ WvT^T -------------
__global__ __launch_bounds__(256) void gemm_v(
    const u16* __restrict__ xbf, const u16* __restrict__ WvT,
    u16* __restrict__ vtmp) {
  __shared__ u16 As[128 * 32];
  __shared__ u16 Bs[128 * 32];
  const int t = threadIdx.x;
  const int lane = t & 63, wid = t >> 6;
  const int l16 = lane & 15, quad = lane >> 4;
  const int wm = wid >> 1, wn = wid & 1;
  const int m0 = blockIdx.y * 128, n0 = blockIdx.x * 128;

  fx4 acc[4][4] = {};
  for (int k0 = 0; k0 < CC; k0 += 32) {
    __syncthreads();
#pragma unroll
    for (int i = 0; i < 2; ++i) {
      int idx = (i * 256 + t) * 8;
      int r = idx >> 5, ko = idx & 31;
      *(uint4*)&As[r * 32 + ko] = *(const uint4*)&xbf[(size_t)(m0 + r) * CC + k0 + ko];
      *(uint4*)&Bs[r * 32 + ko] = *(const uint4*)&WvT[(size_t)(n0 + r) * CC + k0 + ko];
    }
    __syncthreads();
    bf16x8 af[4], bfr[4];
#pragma unroll
    for (int mi = 0; mi < 4; ++mi)
      af[mi] = *(const bf16x8*)&As[(wm * 64 + mi * 16 + l16) * 32 + quad * 8];
#pragma unroll
    for (int ni = 0; ni < 4; ++ni)
      bfr[ni] = *(const bf16x8*)&Bs[(wn * 64 + ni * 16 + l16) * 32 + quad * 8];
#pragma unroll
    for (int mi = 0; mi < 4; ++mi)
#pragma unroll
      for (int ni = 0; ni < 4; ++ni)
        acc[mi][ni] = mfma16(af[mi], bfr[ni], acc[mi][ni]);
  }
#pragma unroll
  for (int mi = 0; mi < 4; ++mi)
#pragma unroll
    for (int ni = 0; ni < 4; ++ni)
#pragma unroll
      for (int r = 0; r < 4; ++r) {
        int row = m0 + wm * 64 + mi * 16 + quad * 4 + r;
        int col = n0 + wn * 64 + ni * 16 + l16;
        vtmp[(size_t)row * CC + col] = f2bf(acc[mi][ni][r]);
      }
}

// ---------------- out-projection GEMM: FLOAT out = A@WoT^T + bias ------------
__global__ __launch_bounds__(256) void gemm_out(
    const u16* __restrict__ A, const u16* __restrict__ BT,
    float* __restrict__ out0, const float* __restrict__ bias0) {
  __shared__ u16 As[128 * 32];
  __shared__ u16 Bs[128 * 32];
  const int t = threadIdx.x;
  const int lane = t & 63, wid = t >> 6;
  const int l16 = lane & 15, quad = lane >> 4;
  const int wm = wid >> 1, wn = wid & 1;
  const int m0 = blockIdx.y * 128, n0 = blockIdx.x * 128;

  fx4 acc[4][4] = {};
  for (int k0 = 0; k0 < CC; k0 += 32) {
    __syncthreads();
#pragma unroll
    for (int i = 0; i < 2; ++i) {
      int idx = (i * 256 + t) * 8;
      int r = idx >> 5, ko = idx & 31;
      *(uint4*)&As[r * 32 + ko] = *(const uint4*)&A[(size_t)(m0 + r) * CC + k0 + ko];
      *(uint4*)&Bs[r * 32 + ko] = *(const uint4*)&BT[(size_t)(n0 + r) * CC + k0 + ko];
    }
    __syncthreads();
    bf16x8 af[4], bfr[4];
#pragma unroll
    for (int mi = 0; mi < 4; ++mi)
      af[mi] = *(const bf16x8*)&As[(wm * 64 + mi * 16 + l16) * 32 + quad * 8];
#pragma unroll
    for (int ni = 0; ni < 4; ++ni)
      bfr[ni] = *(const bf16x8*)&Bs[(wn * 64 + ni * 16 + l16) * 32 + quad * 8];
#pragma unroll
    for (int mi = 0; mi < 4; ++mi)
#pragma unroll
      for (int ni = 0; ni < 4; ++ni)
        acc[mi][ni] = mfma16(af[mi], bfr[ni], acc[mi][ni]);
  }
#pragma unroll
  for (int mi = 0; mi < 4; ++mi)
#pragma unroll
    for (int ni = 0; ni < 4; ++ni)
#pragma unroll
      for (int r = 0; r < 4; ++r) {
        int row = m0 + wm * 64 + mi * 16 + quad * 4 + r;
        int col = n0 + wn * 64 + ni * 16 + l16;
        out0[(size_t)row * CC + col] = acc[mi][ni][r] + bias0[col];
      }
}

// ---------------- U/W suffix-sum tables --------------------------------------
__global__ __launch_bounds__(256) void uw_kernel(
    const u16* __restrict__ qr, const float* __restrict__ Wr,
    float* __restrict__ U, float* __restrict__ W) {
  const int h = blockIdx.y;
  const int t = threadIdx.x;
  const int ty = t >> 5, i = t & 31;
  const int q = blockIdx.x * 8 + ty;
  const u16* qp = qr + ((size_t)h * TT + q) * 64;
  const float* wp = Wr + (size_t)i * (HH * KK) + h * 64;
  float s = 0.0f;
  for (int kx = 0; kx < 64; ++kx) s += bf2f(qp[kx]) * wp[kx];
  __shared__ float u[8][33];
  u[ty][i] = s;
  __syncthreads();
  if (i < 16) {
    float su = 0.f, sw = 0.f;
    for (int j = i; j < 16; ++j) { su += u[ty][j]; sw += u[ty][16 + j]; }
    U[((size_t)h * TT + q) * 16 + i] = su;
    W[((size_t)h * TT + q) * 16 + i] = sw;
  }
}

// ---------------- split-K flash attention, S^T layout ------------------------
// 1D grid 2048; h=blk&7 (XCD pin), ks=(blk>>3)&7, q0=(blk>>6)*64.
__global__ __launch_bounds__(256, 3) void attn_split(
    const u16* __restrict__ qw, const u16* __restrict__ Kw,
    const u16* __restrict__ vT, const float* __restrict__ Ug,
    const float* __restrict__ Wg, const unsigned char* __restrict__ cidx_g,
    u16* __restrict__ o_part, float* __restrict__ m_part,
    float* __restrict__ l_part) {
  const int blk = blockIdx.x;
  const int h = blk & 7;
  const int ks = (blk >> 3) & 7;
  const int q0 = (blk >> 6) * 64;
  const int t = threadIdx.x;
  const int lane = t & 63, w = t >> 6;
  const int l16 = lane & 15, quad = lane >> 4;

  __shared__ unsigned char cidx[TT];
  __shared__ float2 UW[64][17];
  __shared__ u16 Pl[4][16 * 72];

  *(uint2*)&cidx[t * 8] = *(const uint2*)&cidx_g[t * 8];
  for (int i = t; i < 64 * 16; i += 256) {
    int ql = i >> 4, c = i & 15;
    UW[ql][c] = make_float2(Ug[((size_t)h * TT + q0 + ql) * 16 + c],
                            Wg[((size_t)h * TT + q0 + ql) * 16 + c]);
  }
  __syncthreads();

  const int qloc = w * 16 + l16;
  const int q_abs = q0 + qloc;
  const u16* qp = qw + ((size_t)h * TT + q_abs) * 64 + quad * 8;
  const bf16x8 aq0 = *(const bf16x8*)qp;
  const bf16x8 aq1 = *(const bf16x8*)(qp + 32);

  float m_s = -3.0e38f, l_s = 0.0f;
  fx4 o[12] = {};
  const u16* kbase = Kw + (size_t)h * TT * 64;
  const u16* vbase = vT + (size_t)h * VV * TT;

  for (int j0 = ks * JBLK; j0 < (ks + 1) * JBLK; j0 += 64) {
    bf16x8 kf[8];
#pragma unroll
    for (int jt = 0; jt < 4; ++jt) {
      const u16* kp = kbase + (size_t)(j0 + jt * 16 + l16) * 64 + quad * 8;
      kf[jt * 2] = *(const bf16x8*)kp;
      kf[jt * 2 + 1] = *(const bf16x8*)(kp + 32);
    }
    fx4 s[4];
#pragma unroll
    for (int jt = 0; jt < 4; ++jt) {
      fx4 z = {0.f, 0.f, 0.f, 0.f};
      z = mfma16(kf[jt * 2], aq0, z);
      s[jt] = mfma16(kf[jt * 2 + 1], aq1, z);
    }
    const int dbase = j0 + quad * 4 - q_abs;
    int cc[16];
#pragma unroll
    for (int jt = 0; jt < 4; ++jt)
#pragma unroll
      for (int r = 0; r < 4; ++r) {
        int d = dbase + jt * 16 + r;
        cc[jt * 4 + r] = cidx[d < 0 ? -d : d];
      }
    float2 uwv[16];
#pragma unroll
    for (int i = 0; i < 16; ++i) uwv[i] = UW[qloc][cc[i]];
#pragma unroll
    for (int jt = 0; jt < 4; ++jt)
#pragma unroll
      for (int r = 0; r < 4; ++r) {
        int d = dbase + jt * 16 + r;
        float2 z = uwv[jt * 4 + r];
        s[jt][r] += z.x + (d > 0 ? z.y : (d < 0 ? -z.y : 0.0f));
      }
    float mx = s[0][0];
#pragma unroll
    for (int jt = 0; jt < 4; ++jt)
#pragma unroll
      for (int r = 0; r < 4; ++r) mx = fmaxf(mx, s[jt][r]);
    mx = fmaxf(mx, __shfl_xor(mx, 16, 64));
    mx = fmaxf(mx, __shfl_xor(mx, 32, 64));
    float mnew = fmaxf(m_s, mx);
    float alpha = __expf(m_s - mnew);
    float p16[16];
    float ps = 0.0f;
#pragma unroll
    for (int jt = 0; jt < 4; ++jt)
#pragma unroll
      for (int r = 0; r < 4; ++r) {
        float p = __expf(s[jt][r] - mnew);
        p16[jt * 4 + r] = p;
        ps += p;
      }
    ps += __shfl_xor(ps, 16, 64);
    ps += __shfl_xor(ps, 32, 64);
    l_s = l_s * alpha + ps;
    m_s = mnew;
    float a4[4];
#pragma unroll
    for (int r = 0; r < 4; ++r) a4[r] = __shfl(alpha, quad * 4 + r, 16);
#pragma unroll
    for (int vt = 0; vt < 12; ++vt)
#pragma unroll
      for (int r = 0; r < 4; ++r) o[vt][r] *= a4[r];
    bf16x8 bv[12];
#pragma unroll
    for (int vt = 0; vt < 12; ++vt)
      bv[vt] = *(const bf16x8*)(vbase + (size_t)(vt * 16 + l16) * TT + j0 + quad * 8);
    asm volatile("s_waitcnt lgkmcnt(0)" ::: "memory");
#pragma unroll
    for (int jt = 0; jt < 4; ++jt) {
      union { u16 h4[4]; uint2 v; } pk;
#pragma unroll
      for (int r = 0; r < 4; ++r) pk.h4[r] = f2bf(p16[jt * 4 + r]);
      *(uint2*)&Pl[w][l16 * 72 + jt * 16 + quad * 4] = pk.v;
    }
    asm volatile("s_waitcnt lgkmcnt(0)" ::: "memory");
    bf16x8 pf0 = *(const bf16x8*)&Pl[w][l16 * 72 + quad * 8];
    bf16x8 pf1 = *(const bf16x8*)&Pl[w][l16 * 72 + 32 + quad * 8];
#pragma unroll
    for (int vt = 0; vt < 12; ++vt) o[vt] = mfma16(pf0, bv[vt], o[vt]);
#pragma unroll
    for (int vt = 0; vt < 12; ++vt)
      bv[vt] = *(const bf16x8*)(vbase + (size_t)(vt * 16 + l16) * TT + j0 + 32 + quad * 8);
#pragma unroll
    for (int vt = 0; vt < 12; ++vt) o[vt] = mfma16(pf1, bv[vt], o[vt]);
  }

#pragma unroll
  for (int r = 0; r < 4; ++r) {
    int row = q0 + w * 16 + quad * 4 + r;
    size_t base = ((size_t)(ks * HH + h) * TT + row) * VV;
#pragma unroll
    for (int vt = 0; vt < 12; ++vt) o_part[base + vt * 16 + l16] = f2bf(o[vt][r]);
  }
  if (quad == 0) {
    m_part[(size_t)(ks * HH + h) * TT + q_abs] = m_s;
    l_part[(size_t)(ks * HH + h) * TT + q_abs] = l_s;
  }
}

// ---------------- combine split-K partials -> bf16 aout ----------------------
__global__ __launch_bounds__(256) void attn_combine(
    const u16* __restrict__ o_part, const float* __restrict__ m_part,
    const float* __restrict__ l_part, u16* __restrict__ aout) {
  const int h = blockIdx.y;
  const int row = blockIdx.x * 16 + (threadIdx.x >> 4);
  const int c0 = (threadIdx.x & 15) * 12;

  float m[SPLITS], M = -3.0e38f;
#pragma unroll
  for (int s = 0; s < SPLITS; ++s) {
    m[s] = m_part[(size_t)(s * HH + h) * TT + row];
    M = fmaxf(M, m[s]);
  }
  float lsum = 0.0f, wgt[SPLITS];
#pragma unroll
  for (int s = 0; s < SPLITS; ++s) {
    wgt[s] = __expf(m[s] - M);
    lsum += wgt[s] * l_part[(size_t)(s * HH + h) * TT + row];
  }
  float o[12];
#pragma unroll
  for (int j = 0; j < 12; ++j) o[j] = 0.0f;
#pragma unroll
  for (int s = 0; s < SPLITS; ++s) {
    const u16* op = o_part + ((size_t)(s * HH + h) * TT + row) * VV + c0;
    float wgts = wgt[s];
    uint2 u0 = *(const uint2*)&op[0];
    uint2 u1 = *(const uint2*)&op[4];
    uint2 u2 = *(const uint2*)&op[8];
    u32 uu[6] = {u0.x, u0.y, u1.x, u1.y, u2.x, u2.y};
#pragma unroll
    for (int j = 0; j < 6; ++j) {
      o[j * 2 + 0] = fmaf(wgts, bf2f((u16)(uu[j] & 0xFFFF)), o[j * 2 + 0]);
      o[j * 2 + 1] = fmaf(wgts, bf2f((u16)(uu[j] >> 16)), o[j * 2 + 1]);
    }
  }
  float inv = 1.0f / lsum;
  union { u16 hx[12]; uint2 v2[3]; } pk;
#pragma unroll
  for (int j = 0; j < 12; ++j) pk.hx[j] = f2bf(o[j] * inv);
  u16* dst = aout + (size_t)row * CC + h * VV + c0;
  *(uint2*)&dst[0] = pk.v2[0];
  *(uint2*)&dst[4] = pk.v2[1];
  *(uint2*)&dst[8] = pk.v2[2];
}

// ---------------- bf16 transpose for v ---------------------------------------
__global__ __launch_bounds__(256) void transpose_bf16(
    const u16* __restrict__ in, u16* __restrict__ out,
    int in_rs, int out_rs, long in_bs, long out_bs) {
  __shared__ u16 tile[64][68];
  const int t = threadIdx.x;
  const int c0 = blockIdx.x * 64, r0 = blockIdx.y * 64;
  const u16* inp = in + (size_t)blockIdx.z * in_bs;
  u16* outp = out + (size_t)blockIdx.z * out_bs;
#pragma unroll
  for (int i = 0; i < 4; ++i) {
    int idx = i * 256 + t;
    int r = idx >> 4, ch = idx & 15;
    *(uint2*)&tile[r][ch * 4] =
        *(const uint2*)&inp[(size_t)(r0 + r) * in_rs + c0 + ch * 4];
  }
  __syncthreads();
#pragma unroll
  for (int i = 0; i < 4; ++i) {
    int idx = i * 256 + t;
    int r = idx >> 4, ch = idx & 15;
    u16 a0 = tile[ch * 4 + 0][r], a1 = tile[ch * 4 + 1][r];
    u16 a2 = tile[ch * 4 + 2][r], a3 = tile[ch * 4 + 3][r];
    uint2 d;
    d.x = (u32)a0 | ((u32)a1 << 16);
    d.y = (u32)a2 | ((u32)a3 << 16);
    *(uint2*)&outp[(size_t)(c0 + r) * out_rs + r0 + ch * 4] = d;
  }
}

extern "C" void kernel_launch(void* const* d_in, const int* in_sizes, int n_in,
                              void* d_out, int out_size, void* d_ws, size_t ws_size,
                              hipStream_t stream) {
  (void)in_sizes; (void)n_in; (void)out_size; (void)ws_size;
  const float* x   = (const float*)d_in[0];
  const float* Wq  = (const float*)d_in[1];
  const float* Wk  = (const float*)d_in[2];
  const float* Wv  = (const float*)d_in[3];
  const float* Wr  = (const float*)d_in[4];
  const float* rwb = (const float*)d_in[5];
  const float* rrb = (const float*)d_in[6];
  const float* Wo  = (const float*)d_in[7];
  const float* bo  = (const float*)d_in[8];

  char* ws = (char*)d_ws;
  size_t off = 0;
  auto alloc = [&](size_t bytes) -> void* {
    void* p = ws + off;
    off += (bytes + 255) & ~(size_t)255;
    return p;
  };
  u16* WqT  = (u16*)alloc((size_t)512 * 1536 * 2);
  u16* WkT  = (u16*)alloc((size_t)512 * 1536 * 2);
  u16* WvT  = (u16*)alloc((size_t)1536 * 1536 * 2);
  u16* WoT  = (u16*)alloc((size_t)1536 * 1536 * 2);
  u16* xbf  = (u16*)alloc((size_t)TT * CC * 2);
  u16* qw   = (u16*)alloc((size_t)HH * TT * 64 * 2);
  u16* qr   = (u16*)alloc((size_t)HH * TT * 64 * 2);
  u16* Kws  = (u16*)alloc((size_t)HH * TT * 64 * 2);
  u16* vtmp = (u16*)alloc((size_t)TT * CC * 2);
  u16* vTw  = (u16*)alloc((size_t)HH * VV * TT * 2);
  float* Uw = (float*)alloc((size_t)HH * TT * 16 * 4);
  float* Ww = (float*)alloc((size_t)HH * TT * 16 * 4);
  u16* aout = (u16*)alloc((size_t)TT * CC * 2);
  unsigned char* cidx_g = (unsigned char*)alloc(TT);
  u16* o_part   = (u16*)alloc((size_t)SPLITS * HH * TT * VV * 2);
  float* m_part = (float*)alloc((size_t)SPLITS * HH * TT * 4);
  float* l_part = (float*)alloc((size_t)SPLITS * HH * TT * 4);

  prep_kernel<<<dim3(24, 24, 5), 256, 0, stream>>>(Wq, Wk, Wv, Wo,
                                                   WqT, WkT, WvT, WoT, cidx_g);
  xconv_kernel<<<dim3(1536), 256, 0, stream>>>(x, xbf);

  gemm_qk<<<dim3(8, 16), 256, 0, stream>>>(xbf, WqT, WkT, qw, qr, Kws, rwb, rrb);
  gemm_v<<<dim3(12, 16), 256, 0, stream>>>(xbf, WvT, vtmp);

  transpose_bf16<<<dim3(3, 32, 8), 256, 0, stream>>>(vtmp, vTw, 1536, 2048, 192, (long)192 * 2048);
  uw_kernel<<<dim3(256, 8), 256, 0, stream>>>(qr, Wr, Uw, Ww);

  attn_split<<<dim3(2048), 256, 0, stream>>>(qw, Kws, vTw, Uw, Ww, cidx_g,
                                             o_part, m_part, l_part);
  attn_combine<<<dim3(128, 8), 256, 0, stream>>>(o_part, m_part, l_part, aout);

  gemm_out<<<dim3(12, 16), 256, 0, stream>>>(aout, WoT, (float*)d_out, bo);
}

// Round 9
// 325.365 us; speedup vs baseline: 2.1685x; 1.1348x over previous
//
#include <hip/hip_runtime.h>
#include <hip/hip_bf16.h>

typedef unsigned short u16;
typedef unsigned int u32;
typedef __bf16 bf16_t;
typedef bf16_t bf16x8 __attribute__((ext_vector_type(8)));
typedef float fx4 __attribute__((ext_vector_type(4)));

#define TT 2048
#define HH 8
#define KK 64
#define VV 192
#define CC 1536
#define SPLITS 4
#define JBLK (TT / SPLITS)

__device__ __forceinline__ float bf2f(u16 b) {
  union { u32 u; float f; } v; v.u = ((u32)b) << 16; return v.f;
}
__device__ __forceinline__ u16 f2bf(float f) {
  union { float f; u32 u; } v; v.f = f;
  return (u16)((v.u + 0x7FFFu + ((v.u >> 16) & 1u)) >> 16);
}
__device__ __forceinline__ fx4 mfma16(bf16x8 a, bf16x8 b, fx4 c) {
  return __builtin_amdgcn_mfma_f32_16x16x32_bf16(a, b, c, 0, 0, 0);
}

// ------ prep: 4 weight transposes (f32->bf16) + cidx table + x conversion ----
// z=0..3: weight transposes; z=4: cidx (block 0,0); z=5: x f32->bf16.
__global__ __launch_bounds__(256) void prep_kernel(
    const float* __restrict__ Wq, const float* __restrict__ Wk,
    const float* __restrict__ Wv, const float* __restrict__ Wo,
    const float* __restrict__ x,
    u16* __restrict__ WqT, u16* __restrict__ WkT,
    u16* __restrict__ WvT, u16* __restrict__ WoT,
    u16* __restrict__ xbf, unsigned char* __restrict__ cidx_g) {
  const int z = blockIdx.z;
  const int t = threadIdx.x;
  if (z == 4) {
    if (blockIdx.x != 0 || blockIdx.y != 0) return;
    float pr = expf(logf((float)(TT + 1)) / 16.0f);
    float cw[16];
    float wv = pr;
    for (int i = 0; i < 16; ++i) { cw[i] = wv - 1.0f; wv *= pr; }
    for (int idx = t; idx < TT; idx += 256) {
      int c = 15;
      for (int i = 14; i >= 0; --i)
        if (cw[i] > (float)idx) c = i;
      cidx_g[idx] = (unsigned char)c;
    }
    return;
  }
  if (z == 5) {
    const size_t ngroups = (size_t)TT * CC / 8;
    int bid = blockIdx.y * 24 + blockIdx.x;  // 0..575
    for (size_t g = (size_t)bid * 256 + t; g < ngroups; g += (size_t)576 * 256) {
      size_t i = g * 8;
      float4 f0 = *(const float4*)&x[i];
      float4 f1 = *(const float4*)&x[i + 4];
      union { u16 h[8]; uint4 v; } pk;
      pk.h[0] = f2bf(f0.x); pk.h[1] = f2bf(f0.y);
      pk.h[2] = f2bf(f0.z); pk.h[3] = f2bf(f0.w);
      pk.h[4] = f2bf(f1.x); pk.h[5] = f2bf(f1.y);
      pk.h[6] = f2bf(f1.z); pk.h[7] = f2bf(f1.w);
      *(uint4*)&xbf[i] = pk.v;
    }
    return;
  }
  if (z < 2 && blockIdx.x >= 8) return;
  const float* in = (z == 0) ? Wq : (z == 1) ? Wk : (z == 2) ? Wv : Wo;
  u16* out = (z == 0) ? WqT : (z == 1) ? WkT : (z == 2) ? WvT : WoT;
  const int in_rs = (z < 2) ? 512 : 1536;
  const int out_rs = 1536;

  __shared__ u16 tile[64][68];
  const int c0 = blockIdx.x * 64, r0 = blockIdx.y * 64;
#pragma unroll
  for (int i = 0; i < 4; ++i) {
    int idx = i * 256 + t;
    int r = idx >> 4, ch = idx & 15;
    float4 fv = *(const float4*)&in[(size_t)(r0 + r) * in_rs + c0 + ch * 4];
    tile[r][ch * 4 + 0] = f2bf(fv.x);
    tile[r][ch * 4 + 1] = f2bf(fv.y);
    tile[r][ch * 4 + 2] = f2bf(fv.z);
    tile[r][ch * 4 + 3] = f2bf(fv.w);
  }
  __syncthreads();
#pragma unroll
  for (int i = 0; i < 4; ++i) {
    int idx = i * 256 + t;
    int r = idx >> 4, ch = idx & 15;
    u16 a0 = tile[ch * 4 + 0][r], a1 = tile[ch * 4 + 1][r];
    u16 a2 = tile[ch * 4 + 2][r], a3 = tile[ch * 4 + 3][r];
    uint2 d;
    d.x = (u32)a0 | ((u32)a1 << 16);
    d.y = (u32)a2 | ((u32)a3 << 16);
    *(uint2*)&out[(size_t)(c0 + r) * out_rs + r0 + ch * 4] = d;
  }
}

// ---------------- unified QKV projection GEMM (bf16 A) -----------------------
// grid (20,16): cb<4 -> Q (scale+biases), cb<8 -> K, else V plain.
__global__ __launch_bounds__(256) void gemm_qkv(
    const u16* __restrict__ xbf, const u16* __restrict__ WqT,
    const u16* __restrict__ WkT, const u16* __restrict__ WvT,
    u16* __restrict__ qw, u16* __restrict__ qr, u16* __restrict__ Kws,
    u16* __restrict__ vtmp, const float* __restrict__ rwb,
    const float* __restrict__ rrb) {
  __shared__ u16 As[128 * 32];
  __shared__ u16 Bs[128 * 32];
  const int cb = blockIdx.x;
  const u16* BT = (cb < 4) ? WqT : (cb < 8) ? WkT : WvT;
  const int n0 = ((cb < 4) ? cb : (cb < 8) ? cb - 4 : cb - 8) * 128;
  const int t = threadIdx.x;
  const int lane = t & 63, wid = t >> 6;
  const int l16 = lane & 15, quad = lane >> 4;
  const int wm = wid >> 1, wn = wid & 1;
  const int m0 = blockIdx.y * 128;

  fx4 acc[4][4] = {};
  for (int k0 = 0; k0 < CC; k0 += 32) {
    __syncthreads();
#pragma unroll
    for (int i = 0; i < 2; ++i) {
      int idx = (i * 256 + t) * 8;
      int r = idx >> 5, ko = idx & 31;
      *(uint4*)&As[r * 32 + ko] = *(const uint4*)&xbf[(size_t)(m0 + r) * CC + k0 + ko];
      *(uint4*)&Bs[r * 32 + ko] = *(const uint4*)&BT[(size_t)(n0 + r) * CC + k0 + ko];
    }
    __syncthreads();
    bf16x8 af[4], bfr[4];
#pragma unroll
    for (int mi = 0; mi < 4; ++mi)
      af[mi] = *(const bf16x8*)&As[(wm * 64 + mi * 16 + l16) * 32 + quad * 8];
#pragma unroll
    for (int ni = 0; ni < 4; ++ni)
      bfr[ni] = *(const bf16x8*)&Bs[(wn * 64 + ni * 16 + l16) * 32 + quad * 8];
#pragma unroll
    for (int mi = 0; mi < 4; ++mi)
#pragma unroll
      for (int ni = 0; ni < 4; ++ni)
        acc[mi][ni] = mfma16(af[mi], bfr[ni], acc[mi][ni]);
  }

#pragma unroll
  for (int mi = 0; mi < 4; ++mi)
#pragma unroll
    for (int ni = 0; ni < 4; ++ni)
#pragma unroll
      for (int r = 0; r < 4; ++r) {
        int row = m0 + wm * 64 + mi * 16 + quad * 4 + r;
        int col = n0 + wn * 64 + ni * 16 + l16;
        float v = acc[mi][ni][r];
        if (cb < 8) {
          int h = col >> 6, kx = col & 63;
          size_t o = ((size_t)h * TT + row) * 64 + kx;
          if (cb < 4) {
            float qs = v * 0.125f;
            qw[o] = f2bf(qs + rwb[col]);
            qr[o] = f2bf(qs + rrb[col]);
          } else {
            Kws[o] = f2bf(v);
          }
        } else {
          vtmp[(size_t)row * CC + col] = f2bf(v);
        }
      }
}

// ---------------- fused v-transpose + U/W suffix tables ----------------------
// 1D grid 2816: bid<768 -> v transpose tiles; bid>=768 -> uw blocks.
__global__ __launch_bounds__(256) void transuw_kernel(
    const u16* __restrict__ vtmp, u16* __restrict__ vTw,
    const u16* __restrict__ qr, const float* __restrict__ Wr,
    float* __restrict__ U, float* __restrict__ W) {
  __shared__ u16 tile[64][68];
  __shared__ float ubuf[8][33];
  const int bid = blockIdx.x;
  const int t = threadIdx.x;
  if (bid < 768) {
    const int bx = bid % 3, by = (bid / 3) % 32, bz = bid / 96;
    const int c0 = bx * 64, r0 = by * 64;
    const u16* inp = vtmp + (size_t)bz * 192;         // head column offset
    u16* outp = vTw + (size_t)bz * 192 * 2048;
#pragma unroll
    for (int i = 0; i < 4; ++i) {
      int idx = i * 256 + t;
      int r = idx >> 4, ch = idx & 15;
      *(uint2*)&tile[r][ch * 4] =
          *(const uint2*)&inp[(size_t)(r0 + r) * 1536 + c0 + ch * 4];
    }
    __syncthreads();
#pragma unroll
    for (int i = 0; i < 4; ++i) {
      int idx = i * 256 + t;
      int r = idx >> 4, ch = idx & 15;
      u16 a0 = tile[ch * 4 + 0][r], a1 = tile[ch * 4 + 1][r];
      u16 a2 = tile[ch * 4 + 2][r], a3 = tile[ch * 4 + 3][r];
      uint2 d;
      d.x = (u32)a0 | ((u32)a1 << 16);
      d.y = (u32)a2 | ((u32)a3 << 16);
      *(uint2*)&outp[(size_t)(c0 + r) * 2048 + r0 + ch * 4] = d;
    }
  } else {
    const int u_ = bid - 768;               // 0..2047
    const int h = u_ >> 8;
    const int ty = t >> 5, i = t & 31;
    const int q = (u_ & 255) * 8 + ty;
    const u16* qp = qr + ((size_t)h * TT + q) * 64;
    const float* wp = Wr + (size_t)i * (HH * KK) + h * 64;
    float s = 0.0f;
    for (int kx = 0; kx < 64; ++kx) s += bf2f(qp[kx]) * wp[kx];
    ubuf[ty][i] = s;
    __syncthreads();
    if (i < 16) {
      float su = 0.f, sw = 0.f;
      for (int j = i; j < 16; ++j) { su += ubuf[ty][j]; sw += ubuf[ty][16 + j]; }
      U[((size_t)h * TT + q) * 16 + i] = su;
      W[((size_t)h * TT + q) * 16 + i] = sw;
    }
  }
}

// ---------------- out-projection GEMM: FLOAT out = A@WoT^T + bias ------------
__global__ __launch_bounds__(256) void gemm_out(
    const u16* __restrict__ A, const u16* __restrict__ BT,
    float* __restrict__ out0, const float* __restrict__ bias0) {
  __shared__ u16 As[128 * 32];
  __shared__ u16 Bs[128 * 32];
  const int t = threadIdx.x;
  const int lane = t & 63, wid = t >> 6;
  const int l16 = lane & 15, quad = lane >> 4;
  const int wm = wid >> 1, wn = wid & 1;
  const int m0 = blockIdx.y * 128, n0 = blockIdx.x * 128;

  fx4 acc[4][4] = {};
  for (int k0 = 0; k0 < CC; k0 += 32) {
    __syncthreads();
#pragma unroll
    for (int i = 0; i < 2; ++i) {
      int idx = (i * 256 + t) * 8;
      int r = idx >> 5, ko = idx & 31;
      *(uint4*)&As[r * 32 + ko] = *(const uint4*)&A[(size_t)(m0 + r) * CC + k0 + ko];
      *(uint4*)&Bs[r * 32 + ko] = *(const uint4*)&BT[(size_t)(n0 + r) * CC + k0 + ko];
    }
    __syncthreads();
    bf16x8 af[4], bfr[4];
#pragma unroll
    for (int mi = 0; mi < 4; ++mi)
      af[mi] = *(const bf16x8*)&As[(wm * 64 + mi * 16 + l16) * 32 + quad * 8];
#pragma unroll
    for (int ni = 0; ni < 4; ++ni)
      bfr[ni] = *(const bf16x8*)&Bs[(wn * 64 + ni * 16 + l16) * 32 + quad * 8];
#pragma unroll
    for (int mi = 0; mi < 4; ++mi)
#pragma unroll
      for (int ni = 0; ni < 4; ++ni)
        acc[mi][ni] = mfma16(af[mi], bfr[ni], acc[mi][ni]);
  }
#pragma unroll
  for (int mi = 0; mi < 4; ++mi)
#pragma unroll
    for (int ni = 0; ni < 4; ++ni)
#pragma unroll
      for (int r = 0; r < 4; ++r) {
        int row = m0 + wm * 64 + mi * 16 + quad * 4 + r;
        int col = n0 + wn * 64 + ni * 16 + l16;
        out0[(size_t)row * CC + col] = acc[mi][ni][r] + bias0[col];
      }
}

// ---------------- split-K flash attention, S^T layout, pipelined loads -------
// 1D grid 1024; h=blk&7 (XCD pin), ks=(blk>>3)&3, q0=(blk>>5)*64. 8 j-iters.
__global__ __launch_bounds__(256, 2) void attn_split(
    const u16* __restrict__ qw, const u16* __restrict__ Kw,
    const u16* __restrict__ vT, const float* __restrict__ Ug,
    const float* __restrict__ Wg, const unsigned char* __restrict__ cidx_g,
    u16* __restrict__ o_part, float* __restrict__ m_part,
    float* __restrict__ l_part) {
  const int blk = blockIdx.x;
  const int h = blk & 7;
  const int ks = (blk >> 3) & 3;
  const int q0 = (blk >> 5) * 64;
  const int t = threadIdx.x;
  const int lane = t & 63, w = t >> 6;
  const int l16 = lane & 15, quad = lane >> 4;

  __shared__ unsigned char cidx[TT];
  __shared__ float2 UW[64][17];
  __shared__ u16 Pl[4][16 * 72];

  *(uint2*)&cidx[t * 8] = *(const uint2*)&cidx_g[t * 8];
  for (int i = t; i < 64 * 16; i += 256) {
    int ql = i >> 4, c = i & 15;
    UW[ql][c] = make_float2(Ug[((size_t)h * TT + q0 + ql) * 16 + c],
                            Wg[((size_t)h * TT + q0 + ql) * 16 + c]);
  }
  __syncthreads();

  const int qloc = w * 16 + l16;
  const int q_abs = q0 + qloc;
  const u16* qp = qw + ((size_t)h * TT + q_abs) * 64 + quad * 8;
  const bf16x8 aq0 = *(const bf16x8*)qp;
  const bf16x8 aq1 = *(const bf16x8*)(qp + 32);

  float m_s = -3.0e38f, l_s = 0.0f;
  fx4 o[12] = {};
  const u16* kbase = Kw + (size_t)h * TT * 64;
  const u16* vbase = vT + (size_t)h * VV * TT;
  const int jend = (ks + 1) * JBLK;

  for (int j0 = ks * JBLK; j0 < jend; j0 += 64) {
    // K fragments (8 x b128) then V chunk-0 (12 x b128): all in flight together
    bf16x8 kf[8];
#pragma unroll
    for (int jt = 0; jt < 4; ++jt) {
      const u16* kp = kbase + (size_t)(j0 + jt * 16 + l16) * 64 + quad * 8;
      kf[jt * 2] = *(const bf16x8*)kp;
      kf[jt * 2 + 1] = *(const bf16x8*)(kp + 32);
    }
    bf16x8 bv0[12];
#pragma unroll
    for (int vt = 0; vt < 12; ++vt)
      bv0[vt] = *(const bf16x8*)(vbase + (size_t)(vt * 16 + l16) * TT + j0 + quad * 8);
    // S^T = K·Q^T (rows j, cols q)
    fx4 s[4];
#pragma unroll
    for (int jt = 0; jt < 4; ++jt) {
      fx4 z = {0.f, 0.f, 0.f, 0.f};
      z = mfma16(kf[jt * 2], aq0, z);
      s[jt] = mfma16(kf[jt * 2 + 1], aq1, z);
    }
    // rel term
    const int dbase = j0 + quad * 4 - q_abs;
    int cc[16];
#pragma unroll
    for (int jt = 0; jt < 4; ++jt)
#pragma unroll
      for (int r = 0; r < 4; ++r) {
        int d = dbase + jt * 16 + r;
        cc[jt * 4 + r] = cidx[d < 0 ? -d : d];
      }
    float2 uwv[16];
#pragma unroll
    for (int i = 0; i < 16; ++i) uwv[i] = UW[qloc][cc[i]];
#pragma unroll
    for (int jt = 0; jt < 4; ++jt)
#pragma unroll
      for (int r = 0; r < 4; ++r) {
        int d = dbase + jt * 16 + r;
        float2 z = uwv[jt * 4 + r];
        s[jt][r] += z.x + (d > 0 ? z.y : (d < 0 ? -z.y : 0.0f));
      }
    // per-lane online softmax + quad-pair reduction
    float mx = s[0][0];
#pragma unroll
    for (int jt = 0; jt < 4; ++jt)
#pragma unroll
      for (int r = 0; r < 4; ++r) mx = fmaxf(mx, s[jt][r]);
    mx = fmaxf(mx, __shfl_xor(mx, 16, 64));
    mx = fmaxf(mx, __shfl_xor(mx, 32, 64));
    float mnew = fmaxf(m_s, mx);
    float alpha = __expf(m_s - mnew);
    float p16[16];
    float ps = 0.0f;
#pragma unroll
    for (int jt = 0; jt < 4; ++jt)
#pragma unroll
      for (int r = 0; r < 4; ++r) {
        float p = __expf(s[jt][r] - mnew);
        p16[jt * 4 + r] = p;
        ps += p;
      }
    ps += __shfl_xor(ps, 16, 64);
    ps += __shfl_xor(ps, 32, 64);
    l_s = l_s * alpha + ps;
    m_s = mnew;
    float a4[4];
#pragma unroll
    for (int r = 0; r < 4; ++r) a4[r] = __shfl(alpha, quad * 4 + r, 16);
#pragma unroll
    for (int vt = 0; vt < 12; ++vt)
#pragma unroll
      for (int r = 0; r < 4; ++r) o[vt][r] *= a4[r];
    // P -> LDS (wave-private; DS ops in-order per wave, no pre-drain needed)
#pragma unroll
    for (int jt = 0; jt < 4; ++jt) {
      union { u16 h4[4]; uint2 v; } pk;
#pragma unroll
      for (int r = 0; r < 4; ++r) pk.h4[r] = f2bf(p16[jt * 4 + r]);
      *(uint2*)&Pl[w][l16 * 72 + jt * 16 + quad * 4] = pk.v;
    }
    // V chunk-1 loads in flight across the LDS drain + pf reads + PV0
    bf16x8 bv1[12];
#pragma unroll
    for (int vt = 0; vt < 12; ++vt)
      bv1[vt] = *(const bf16x8*)(vbase + (size_t)(vt * 16 + l16) * TT + j0 + 32 + quad * 8);
    asm volatile("s_waitcnt lgkmcnt(0)" ::: "memory");
    bf16x8 pf0 = *(const bf16x8*)&Pl[w][l16 * 72 + quad * 8];
    bf16x8 pf1 = *(const bf16x8*)&Pl[w][l16 * 72 + 32 + quad * 8];
#pragma unroll
    for (int vt = 0; vt < 12; ++vt) o[vt] = mfma16(pf0, bv0[vt], o[vt]);
#pragma unroll
    for (int vt = 0; vt < 12; ++vt) o[vt] = mfma16(pf1, bv1[vt], o[vt]);
  }

#pragma unroll
  for (int r = 0; r < 4; ++r) {
    int row = q0 + w * 16 + quad * 4 + r;
    size_t base = ((size_t)(ks * HH + h) * TT + row) * VV;
#pragma unroll
    for (int vt = 0; vt < 12; ++vt) o_part[base + vt * 16 + l16] = f2bf(o[vt][r]);
  }
  if (quad == 0) {
    m_part[(size_t)(ks * HH + h) * TT + q_abs] = m_s;
    l_part[(size_t)(ks * HH + h) * TT + q_abs] = l_s;
  }
}

// ---------------- combine split-K partials -> bf16 aout ----------------------
__global__ __launch_bounds__(256) void attn_combine(
    const u16* __restrict__ o_part, const float* __restrict__ m_part,
    const float* __restrict__ l_part, u16* __restrict__ aout) {
  const int h = blockIdx.y;
  const int row = blockIdx.x * 16 + (threadIdx.x >> 4);
  const int c0 = (threadIdx.x & 15) * 12;

  float m[SPLITS], M = -3.0e38f;
#pragma unroll
  for (int s = 0; s < SPLITS; ++s) {
    m[s] = m_part[(size_t)(s * HH + h) * TT + row];
    M = fmaxf(M, m[s]);
  }
  float lsum = 0.0f, wgt[SPLITS];
#pragma unroll
  for (int s = 0; s < SPLITS; ++s) {
    wgt[s] = __expf(m[s] - M);
    lsum += wgt[s] * l_part[(size_t)(s * HH + h) * TT + row];
  }
  float o[12];
#pragma unroll
  for (int j = 0; j < 12; ++j) o[j] = 0.0f;
#pragma unroll
  for (int s = 0; s < SPLITS; ++s) {
    const u16* op = o_part + ((size_t)(s * HH + h) * TT + row) * VV + c0;
    float wgts = wgt[s];
    uint2 u0 = *(const uint2*)&op[0];
    uint2 u1 = *(const uint2*)&op[4];
    uint2 u2 = *(const uint2*)&op[8];
    u32 uu[6] = {u0.x, u0.y, u1.x, u1.y, u2.x, u2.y};
#pragma unroll
    for (int j = 0; j < 6; ++j) {
      o[j * 2 + 0] = fmaf(wgts, bf2f((u16)(uu[j] & 0xFFFF)), o[j * 2 + 0]);
      o[j * 2 + 1] = fmaf(wgts, bf2f((u16)(uu[j] >> 16)), o[j * 2 + 1]);
    }
  }
  float inv = 1.0f / lsum;
  union { u16 hx[12]; uint2 v2[3]; } pk;
#pragma unroll
  for (int j = 0; j < 12; ++j) pk.hx[j] = f2bf(o[j] * inv);
  u16* dst = aout + (size_t)row * CC + h * VV + c0;
  *(uint2*)&dst[0] = pk.v2[0];
  *(uint2*)&dst[4] = pk.v2[1];
  *(uint2*)&dst[8] = pk.v2[2];
}

extern "C" void kernel_launch(void* const* d_in, const int* in_sizes, int n_in,
                              void* d_out, int out_size, void* d_ws, size_t ws_size,
                              hipStream_t stream) {
  (void)in_sizes; (void)n_in; (void)out_size; (void)ws_size;
  const float* x   = (const float*)d_in[0];
  const float* Wq  = (const float*)d_in[1];
  const float* Wk  = (const float*)d_in[2];
  const float* Wv  = (const float*)d_in[3];
  const float* Wr  = (const float*)d_in[4];
  const float* rwb = (const float*)d_in[5];
  const float* rrb = (const float*)d_in[6];
  const float* Wo  = (const float*)d_in[7];
  const float* bo  = (const float*)d_in[8];

  char* ws = (char*)d_ws;
  size_t off = 0;
  auto alloc = [&](size_t bytes) -> void* {
    void* p = ws + off;
    off += (bytes + 255) & ~(size_t)255;
    return p;
  };
  u16* WqT  = (u16*)alloc((size_t)512 * 1536 * 2);
  u16* WkT  = (u16*)alloc((size_t)512 * 1536 * 2);
  u16* WvT  = (u16*)alloc((size_t)1536 * 1536 * 2);
  u16* WoT  = (u16*)alloc((size_t)1536 * 1536 * 2);
  u16* xbf  = (u16*)alloc((size_t)TT * CC * 2);
  u16* qw   = (u16*)alloc((size_t)HH * TT * 64 * 2);
  u16* qr   = (u16*)alloc((size_t)HH * TT * 64 * 2);
  u16* Kws  = (u16*)alloc((size_t)HH * TT * 64 * 2);
  u16* vtmp = (u16*)alloc((size_t)TT * CC * 2);
  u16* vTw  = (u16*)alloc((size_t)HH * VV * TT * 2);
  float* Uw = (float*)alloc((size_t)HH * TT * 16 * 4);
  float* Ww = (float*)alloc((size_t)HH * TT * 16 * 4);
  u16* aout = (u16*)alloc((size_t)TT * CC * 2);
  unsigned char* cidx_g = (unsigned char*)alloc(TT);
  u16* o_part   = (u16*)alloc((size_t)SPLITS * HH * TT * VV * 2);
  float* m_part = (float*)alloc((size_t)SPLITS * HH * TT * 4);
  float* l_part = (float*)alloc((size_t)SPLITS * HH * TT * 4);

  prep_kernel<<<dim3(24, 24, 6), 256, 0, stream>>>(Wq, Wk, Wv, Wo, x,
                                                   WqT, WkT, WvT, WoT, xbf, cidx_g);
  gemm_qkv<<<dim3(20, 16), 256, 0, stream>>>(xbf, WqT, WkT, WvT,
                                             qw, qr, Kws, vtmp, rwb, rrb);
  transuw_kernel<<<dim3(2816), 256, 0, stream>>>(vtmp, vTw, qr, Wr, Uw, Ww);
  attn_split<<<dim3(1024), 256, 0, stream>>>(qw, Kws, vTw, Uw, Ww, cidx_g,
                                             o_part, m_part, l_part);
  attn_combine<<<dim3(128, 8), 256, 0, stream>>>(o_part, m_part, l_part, aout);
  gemm_out<<<dim3(12, 16), 256, 0, stream>>>(aout, WoT, (float*)d_out, bo);
}

// Round 10
// 246.458 us; speedup vs baseline: 2.8627x; 1.3202x over previous
//
#include <hip/hip_runtime.h>
#include <hip/hip_bf16.h>

typedef unsigned short u16;
typedef unsigned int u32;
typedef __bf16 bf16_t;
typedef bf16_t bf16x8 __attribute__((ext_vector_type(8)));
typedef float fx4 __attribute__((ext_vector_type(4)));

#define TT 2048
#define HH 8
#define KK 64
#define VV 192
#define CC 1536
#define SPLITS 3

__device__ __forceinline__ float bf2f(u16 b) {
  union { u32 u; float f; } v; v.u = ((u32)b) << 16; return v.f;
}
__device__ __forceinline__ u16 f2bf(float f) {
  union { float f; u32 u; } v; v.f = f;
  return (u16)((v.u + 0x7FFFu + ((v.u >> 16) & 1u)) >> 16);
}
__device__ __forceinline__ fx4 mfma16(bf16x8 a, bf16x8 b, fx4 c) {
  return __builtin_amdgcn_mfma_f32_16x16x32_bf16(a, b, c, 0, 0, 0);
}

// ------ prep: weight transposes + cidx/WrT/dW tables + x conversion ----------
// z=0..3: weight transposes; z=4 (block 0,0): tables; z=5: x f32->bf16.
__global__ __launch_bounds__(256) void prep_kernel(
    const float* __restrict__ Wq, const float* __restrict__ Wk,
    const float* __restrict__ Wv, const float* __restrict__ Wo,
    const float* __restrict__ x, const float* __restrict__ Wr,
    const float* __restrict__ rwb, const float* __restrict__ rrb,
    u16* __restrict__ WqT, u16* __restrict__ WkT,
    u16* __restrict__ WvT, u16* __restrict__ WoT,
    u16* __restrict__ xbf, unsigned char* __restrict__ cidx_g,
    u16* __restrict__ WrT, float* __restrict__ dW) {
  const int z = blockIdx.z;
  const int t = threadIdx.x;
  if (z == 4) {
    if (blockIdx.x != 0 || blockIdx.y != 0) return;
    // cidx: borzoi center-width category per |distance|
    float pr = expf(logf((float)(TT + 1)) / 16.0f);
    float cw[16];
    float wv = pr;
    for (int i = 0; i < 16; ++i) { cw[i] = wv - 1.0f; wv *= pr; }
    for (int idx = t; idx < TT; idx += 256) {
      int c = 15;
      for (int i = 14; i >= 0; --i)
        if (cw[i] > (float)idx) c = i;
      cidx_g[idx] = (unsigned char)c;
    }
    // WrT[h][i][k] bf16 from Wr f32 [32][512]
    for (int idx = t; idx < 8 * 32 * 64; idx += 256) {
      int hh = idx >> 11, rem = idx & 2047;
      int i = rem >> 6, k = rem & 63;
      WrT[idx] = f2bf(Wr[i * 512 + hh * 64 + k]);
    }
    // dW[h*32+i] = sum_k (rrb - rwb)[h*64+k] * Wr[i][h*64+k]
    {
      int hh = t >> 5, i = t & 31;
      float s = 0.0f;
      for (int k = 0; k < 64; ++k)
        s += (rrb[hh * 64 + k] - rwb[hh * 64 + k]) * Wr[i * 512 + hh * 64 + k];
      dW[t] = s;
    }
    return;
  }
  if (z == 5) {
    const size_t ngroups = (size_t)TT * CC / 8;
    int bid = blockIdx.y * 24 + blockIdx.x;  // 0..575
    for (size_t g = (size_t)bid * 256 + t; g < ngroups; g += (size_t)576 * 256) {
      size_t i = g * 8;
      float4 f0 = *(const float4*)&x[i];
      float4 f1 = *(const float4*)&x[i + 4];
      union { u16 h[8]; uint4 v; } pk;
      pk.h[0] = f2bf(f0.x); pk.h[1] = f2bf(f0.y);
      pk.h[2] = f2bf(f0.z); pk.h[3] = f2bf(f0.w);
      pk.h[4] = f2bf(f1.x); pk.h[5] = f2bf(f1.y);
      pk.h[6] = f2bf(f1.z); pk.h[7] = f2bf(f1.w);
      *(uint4*)&xbf[i] = pk.v;
    }
    return;
  }
  if (z < 2 && blockIdx.x >= 8) return;
  const float* in = (z == 0) ? Wq : (z == 1) ? Wk : (z == 2) ? Wv : Wo;
  u16* out = (z == 0) ? WqT : (z == 1) ? WkT : (z == 2) ? WvT : WoT;
  const int in_rs = (z < 2) ? 512 : 1536;
  const int out_rs = 1536;

  __shared__ u16 tile[64][68];
  const int c0 = blockIdx.x * 64, r0 = blockIdx.y * 64;
#pragma unroll
  for (int i = 0; i < 4; ++i) {
    int idx = i * 256 + t;
    int r = idx >> 4, ch = idx & 15;
    float4 fv = *(const float4*)&in[(size_t)(r0 + r) * in_rs + c0 + ch * 4];
    tile[r][ch * 4 + 0] = f2bf(fv.x);
    tile[r][ch * 4 + 1] = f2bf(fv.y);
    tile[r][ch * 4 + 2] = f2bf(fv.z);
    tile[r][ch * 4 + 3] = f2bf(fv.w);
  }
  __syncthreads();
#pragma unroll
  for (int i = 0; i < 4; ++i) {
    int idx = i * 256 + t;
    int r = idx >> 4, ch = idx & 15;
    u16 a0 = tile[ch * 4 + 0][r], a1 = tile[ch * 4 + 1][r];
    u16 a2 = tile[ch * 4 + 2][r], a3 = tile[ch * 4 + 3][r];
    uint2 d;
    d.x = (u32)a0 | ((u32)a1 << 16);
    d.y = (u32)a2 | ((u32)a3 << 16);
    *(uint2*)&out[(size_t)(c0 + r) * out_rs + r0 + ch * 4] = d;
  }
}

// ---------------- unified QKV projection GEMM (bf16 A) -----------------------
// grid (20,16): cb<4 -> Q (scale+bias->qw), cb<8 -> K, else V (direct vT write)
__global__ __launch_bounds__(256) void gemm_qkv(
    const u16* __restrict__ xbf, const u16* __restrict__ WqT,
    const u16* __restrict__ WkT, const u16* __restrict__ WvT,
    u16* __restrict__ qw, u16* __restrict__ Kws, u16* __restrict__ vTw,
    const float* __restrict__ rwb) {
  __shared__ u16 As[128 * 32];
  __shared__ u16 Bs[128 * 32];
  const int cb = blockIdx.x;
  const u16* BT = (cb < 4) ? WqT : (cb < 8) ? WkT : WvT;
  const int n0 = ((cb < 4) ? cb : (cb < 8) ? cb - 4 : cb - 8) * 128;
  const int t = threadIdx.x;
  const int lane = t & 63, wid = t >> 6;
  const int l16 = lane & 15, quad = lane >> 4;
  const int wm = wid >> 1, wn = wid & 1;
  const int m0 = blockIdx.y * 128;

  fx4 acc[4][4] = {};
  for (int k0 = 0; k0 < CC; k0 += 32) {
    __syncthreads();
#pragma unroll
    for (int i = 0; i < 2; ++i) {
      int idx = (i * 256 + t) * 8;
      int r = idx >> 5, ko = idx & 31;
      *(uint4*)&As[r * 32 + ko] = *(const uint4*)&xbf[(size_t)(m0 + r) * CC + k0 + ko];
      *(uint4*)&Bs[r * 32 + ko] = *(const uint4*)&BT[(size_t)(n0 + r) * CC + k0 + ko];
    }
    __syncthreads();
    bf16x8 af[4], bfr[4];
#pragma unroll
    for (int mi = 0; mi < 4; ++mi)
      af[mi] = *(const bf16x8*)&As[(wm * 64 + mi * 16 + l16) * 32 + quad * 8];
#pragma unroll
    for (int ni = 0; ni < 4; ++ni)
      bfr[ni] = *(const bf16x8*)&Bs[(wn * 64 + ni * 16 + l16) * 32 + quad * 8];
#pragma unroll
    for (int mi = 0; mi < 4; ++mi)
#pragma unroll
      for (int ni = 0; ni < 4; ++ni)
        acc[mi][ni] = mfma16(af[mi], bfr[ni], acc[mi][ni]);
  }

#pragma unroll
  for (int mi = 0; mi < 4; ++mi)
#pragma unroll
    for (int ni = 0; ni < 4; ++ni) {
      int col = n0 + wn * 64 + ni * 16 + l16;
      int row0 = m0 + wm * 64 + mi * 16 + quad * 4;
      if (cb < 8) {
        int h = col >> 6, kx = col & 63;
#pragma unroll
        for (int r = 0; r < 4; ++r) {
          float v = acc[mi][ni][r];
          size_t o = ((size_t)h * TT + row0 + r) * 64 + kx;
          if (cb < 4) qw[o] = f2bf(v * 0.125f + rwb[col]);
          else Kws[o] = f2bf(v);
        }
      } else {
        // direct transposed V write: vTw[h][vv][t], 4 consecutive t per lane
        int h = col / 192, vv = col - h * 192;
        union { u16 h4[4]; uint2 v2; } pk;
#pragma unroll
        for (int r = 0; r < 4; ++r) pk.h4[r] = f2bf(acc[mi][ni][r]);
        *(uint2*)&vTw[(size_t)h * VV * TT + (size_t)vv * TT + row0] = pk.v2;
      }
    }
}

// ---------------- out-projection GEMM: FLOAT out = A@WoT^T + bias ------------
__global__ __launch_bounds__(256) void gemm_out(
    const u16* __restrict__ A, const u16* __restrict__ BT,
    float* __restrict__ out0, const float* __restrict__ bias0) {
  __shared__ u16 As[128 * 32];
  __shared__ u16 Bs[128 * 32];
  const int t = threadIdx.x;
  const int lane = t & 63, wid = t >> 6;
  const int l16 = lane & 15, quad = lane >> 4;
  const int wm = wid >> 1, wn = wid & 1;
  const int m0 = blockIdx.y * 128, n0 = blockIdx.x * 128;

  fx4 acc[4][4] = {};
  for (int k0 = 0; k0 < CC; k0 += 32) {
    __syncthreads();
#pragma unroll
    for (int i = 0; i < 2; ++i) {
      int idx = (i * 256 + t) * 8;
      int r = idx >> 5, ko = idx & 31;
      *(uint4*)&As[r * 32 + ko] = *(const uint4*)&A[(size_t)(m0 + r) * CC + k0 + ko];
      *(uint4*)&Bs[r * 32 + ko] = *(const uint4*)&BT[(size_t)(n0 + r) * CC + k0 + ko];
    }
    __syncthreads();
    bf16x8 af[4], bfr[4];
#pragma unroll
    for (int mi = 0; mi < 4; ++mi)
      af[mi] = *(const bf16x8*)&As[(wm * 64 + mi * 16 + l16) * 32 + quad * 8];
#pragma unroll
    for (int ni = 0; ni < 4; ++ni)
      bfr[ni] = *(const bf16x8*)&Bs[(wn * 64 + ni * 16 + l16) * 32 + quad * 8];
#pragma unroll
    for (int mi = 0; mi < 4; ++mi)
#pragma unroll
      for (int ni = 0; ni < 4; ++ni)
        acc[mi][ni] = mfma16(af[mi], bfr[ni], acc[mi][ni]);
  }
#pragma unroll
  for (int mi = 0; mi < 4; ++mi)
#pragma unroll
    for (int ni = 0; ni < 4; ++ni)
#pragma unroll
      for (int r = 0; r < 4; ++r) {
        int row = m0 + wm * 64 + mi * 16 + quad * 4 + r;
        int col = n0 + wn * 64 + ni * 16 + l16;
        out0[(size_t)row * CC + col] = acc[mi][ni][r] + bias0[col];
      }
}

// ---------------- split-K flash attention, LDS-staged K/V --------------------
// grid 768: h=blk&7 (XCD pin), ks=(blk>>3)%3, q0=((blk>>3)/3)*64.
// j-ranges: [0,704) [704,1408) [1408,2048). K/V staged to LDS per 64-j tile
// with XOR-swizzled 16B chunks (chunk ^= row&7) -> conflict-free frag reads.
// UW tables computed in-kernel via MFMA (u = qw.Wr^T + dW).
__global__ __launch_bounds__(256, 3) void attn_split(
    const u16* __restrict__ qw, const u16* __restrict__ Kw,
    const u16* __restrict__ vT, const u16* __restrict__ WrT,
    const float* __restrict__ dW, const unsigned char* __restrict__ cidx_g,
    u16* __restrict__ o_part, float* __restrict__ m_part,
    float* __restrict__ l_part) {
  const int blk = blockIdx.x;
  const int h = blk & 7;
  const int g = blk >> 3;
  const int ks = g % 3;
  const int q0 = (g / 3) * 64;
  const int t = threadIdx.x;
  const int lane = t & 63, w = t >> 6;
  const int l16 = lane & 15, quad = lane >> 4;

  __shared__ u16 KsL[64 * 64];         //  8192 B
  __shared__ u16 VsL[192 * 64];        // 24576 B
  __shared__ float2 UW[64][17];        //  8704 B
  __shared__ unsigned char cidx[TT];   //  2048 B
  __shared__ u16 Pl[4][16 * 72];       //  9216 B (u_raw scratch pre-loop)

  *(uint2*)&cidx[t * 8] = *(const uint2*)&cidx_g[t * 8];

  const int qloc = w * 16 + l16;
  const int q_abs = q0 + qloc;
  const u16* qp = qw + ((size_t)h * TT + q_abs) * 64 + quad * 8;
  const bf16x8 aq0 = *(const bf16x8*)qp;
  const bf16x8 aq1 = *(const bf16x8*)(qp + 32);

  // ---- UW build: u[q][i] = qw[q].WrT_h[i] + dW[h][i]; suffix sums ----
  {
    const u16* wrt = WrT + h * 32 * 64;
    bf16x8 wb00 = *(const bf16x8*)&wrt[l16 * 64 + quad * 8];
    bf16x8 wb01 = *(const bf16x8*)&wrt[l16 * 64 + 32 + quad * 8];
    bf16x8 wb10 = *(const bf16x8*)&wrt[(16 + l16) * 64 + quad * 8];
    bf16x8 wb11 = *(const bf16x8*)&wrt[(16 + l16) * 64 + 32 + quad * 8];
    fx4 u0 = {}, u1 = {};
    u0 = mfma16(aq0, wb00, u0); u0 = mfma16(aq1, wb01, u0);
    u1 = mfma16(aq0, wb10, u1); u1 = mfma16(aq1, wb11, u1);
    float dw0 = dW[h * 32 + l16], dw1 = dW[h * 32 + 16 + l16];
    float* u_raw = (float*)&Pl[0][0];   // [64][33]
#pragma unroll
    for (int r = 0; r < 4; ++r) {
      int qrow = w * 16 + quad * 4 + r;
      u_raw[qrow * 33 + l16] = u0[r] + dw0;
      u_raw[qrow * 33 + 16 + l16] = u1[r] + dw1;
    }
    __syncthreads();
    if (t < 64) {
      float su = 0.f, sw = 0.f;
      float Uv[16], Wv[16];
#pragma unroll
      for (int c = 15; c >= 0; --c) {
        su += u_raw[t * 33 + c]; Uv[c] = su;
        sw += u_raw[t * 33 + 16 + c]; Wv[c] = sw;
      }
#pragma unroll
      for (int c = 0; c < 16; ++c) UW[t][c] = make_float2(Uv[c], Wv[c]);
    }
  }

  float m_s = -3.0e38f, l_s = 0.0f;
  fx4 o[12] = {};
  const u16* kbase = Kw + (size_t)h * TT * 64;
  const u16* vbase = vT + (size_t)h * VV * TT;
  const int jtab[4] = {0, 704, 1408, 2048};
  const int jbeg = jtab[ks], jfin = jtab[ks + 1];

  for (int j0 = jbeg; j0 < jfin; j0 += 64) {
    __syncthreads();  // previous tile's LDS reads done (covers UW build 1st it)
    // ---- cooperative staging: K 8KB (2 chunks/thr) + V 24KB (6 chunks/thr) --
    uint4 kv[2], vv4[6];
#pragma unroll
    for (int i = 0; i < 2; ++i) {
      int chunk = i * 256 + t;
      int j = chunk >> 3, c = (chunk & 7) ^ (j & 7);
      kv[i] = *(const uint4*)&kbase[(size_t)(j0 + j) * 64 + c * 8];
    }
#pragma unroll
    for (int i = 0; i < 6; ++i) {
      int chunk = i * 256 + t;
      int v = chunk >> 3, c = (chunk & 7) ^ (v & 7);
      vv4[i] = *(const uint4*)&vbase[(size_t)v * TT + j0 + c * 8];
    }
#pragma unroll
    for (int i = 0; i < 2; ++i) *(uint4*)&KsL[(i * 256 + t) * 8] = kv[i];
#pragma unroll
    for (int i = 0; i < 6; ++i) *(uint4*)&VsL[(i * 256 + t) * 8] = vv4[i];
    __syncthreads();

    // ---- K fragments from LDS, S^T = K.Q^T ----
    bf16x8 kf[8];
#pragma unroll
    for (int jt = 0; jt < 4; ++jt) {
      int j = jt * 16 + l16;
      kf[jt * 2]     = *(const bf16x8*)&KsL[j * 64 + ((quad) ^ (j & 7)) * 8];
      kf[jt * 2 + 1] = *(const bf16x8*)&KsL[j * 64 + ((quad + 4) ^ (j & 7)) * 8];
    }
    fx4 s[4];
#pragma unroll
    for (int jt = 0; jt < 4; ++jt) {
      fx4 z = {0.f, 0.f, 0.f, 0.f};
      z = mfma16(kf[jt * 2], aq0, z);
      s[jt] = mfma16(kf[jt * 2 + 1], aq1, z);
    }
    // ---- rel term ----
    const int dbase = j0 + quad * 4 - q_abs;
    int cc[16];
#pragma unroll
    for (int jt = 0; jt < 4; ++jt)
#pragma unroll
      for (int r = 0; r < 4; ++r) {
        int d = dbase + jt * 16 + r;
        cc[jt * 4 + r] = cidx[d < 0 ? -d : d];
      }
    float2 uwv[16];
#pragma unroll
    for (int i = 0; i < 16; ++i) uwv[i] = UW[qloc][cc[i]];
#pragma unroll
    for (int jt = 0; jt < 4; ++jt)
#pragma unroll
      for (int r = 0; r < 4; ++r) {
        int d = dbase + jt * 16 + r;
        float2 z = uwv[jt * 4 + r];
        s[jt][r] += z.x + (d > 0 ? z.y : (d < 0 ? -z.y : 0.0f));
      }
    // ---- per-lane online softmax + cross-quad reduction ----
    float mx = s[0][0];
#pragma unroll
    for (int jt = 0; jt < 4; ++jt)
#pragma unroll
      for (int r = 0; r < 4; ++r) mx = fmaxf(mx, s[jt][r]);
    mx = fmaxf(mx, __shfl_xor(mx, 16, 64));
    mx = fmaxf(mx, __shfl_xor(mx, 32, 64));
    float mnew = fmaxf(m_s, mx);
    float alpha = __expf(m_s - mnew);
    float p16[16];
    float ps = 0.0f;
#pragma unroll
    for (int jt = 0; jt < 4; ++jt)
#pragma unroll
      for (int r = 0; r < 4; ++r) {
        float p = __expf(s[jt][r] - mnew);
        p16[jt * 4 + r] = p;
        ps += p;
      }
    ps += __shfl_xor(ps, 16, 64);
    ps += __shfl_xor(ps, 32, 64);
    l_s = l_s * alpha + ps;
    m_s = mnew;
    float a4[4];
#pragma unroll
    for (int r = 0; r < 4; ++r) a4[r] = __shfl(alpha, quad * 4 + r, 16);
#pragma unroll
    for (int vt = 0; vt < 12; ++vt)
#pragma unroll
      for (int r = 0; r < 4; ++r) o[vt][r] *= a4[r];
    // ---- P -> LDS (wave-private) -> A-operand ----
#pragma unroll
    for (int jt = 0; jt < 4; ++jt) {
      union { u16 h4[4]; uint2 v; } pk;
#pragma unroll
      for (int r = 0; r < 4; ++r) pk.h4[r] = f2bf(p16[jt * 4 + r]);
      *(uint2*)&Pl[w][l16 * 72 + jt * 16 + quad * 4] = pk.v;
    }
    asm volatile("s_waitcnt lgkmcnt(0)" ::: "memory");
    bf16x8 pf0 = *(const bf16x8*)&Pl[w][l16 * 72 + quad * 8];
    bf16x8 pf1 = *(const bf16x8*)&Pl[w][l16 * 72 + 32 + quad * 8];
    // ---- PV from LDS V tile ----
#pragma unroll
    for (int vt = 0; vt < 12; ++vt) {
      int v = vt * 16 + l16;
      bf16x8 bv = *(const bf16x8*)&VsL[v * 64 + ((quad) ^ (v & 7)) * 8];
      o[vt] = mfma16(pf0, bv, o[vt]);
    }
#pragma unroll
    for (int vt = 0; vt < 12; ++vt) {
      int v = vt * 16 + l16;
      bf16x8 bv = *(const bf16x8*)&VsL[v * 64 + ((quad + 4) ^ (v & 7)) * 8];
      o[vt] = mfma16(pf1, bv, o[vt]);
    }
  }

#pragma unroll
  for (int r = 0; r < 4; ++r) {
    int row = q0 + w * 16 + quad * 4 + r;
    size_t base = ((size_t)(ks * HH + h) * TT + row) * VV;
#pragma unroll
    for (int vt = 0; vt < 12; ++vt) o_part[base + vt * 16 + l16] = f2bf(o[vt][r]);
  }
  if (quad == 0) {
    m_part[(size_t)(ks * HH + h) * TT + q_abs] = m_s;
    l_part[(size_t)(ks * HH + h) * TT + q_abs] = l_s;
  }
}

// ---------------- combine split-K partials -> bf16 aout ----------------------
__global__ __launch_bounds__(256) void attn_combine(
    const u16* __restrict__ o_part, const float* __restrict__ m_part,
    const float* __restrict__ l_part, u16* __restrict__ aout) {
  const int h = blockIdx.y;
  const int row = blockIdx.x * 16 + (threadIdx.x >> 4);
  const int c0 = (threadIdx.x & 15) * 12;

  float m[SPLITS], M = -3.0e38f;
#pragma unroll
  for (int s = 0; s < SPLITS; ++s) {
    m[s] = m_part[(size_t)(s * HH + h) * TT + row];
    M = fmaxf(M, m[s]);
  }
  float lsum = 0.0f, wgt[SPLITS];
#pragma unroll
  for (int s = 0; s < SPLITS; ++s) {
    wgt[s] = __expf(m[s] - M);
    lsum += wgt[s] * l_part[(size_t)(s * HH + h) * TT + row];
  }
  float o[12];
#pragma unroll
  for (int j = 0; j < 12; ++j) o[j] = 0.0f;
#pragma unroll
  for (int s = 0; s < SPLITS; ++s) {
    const u16* op = o_part + ((size_t)(s * HH + h) * TT + row) * VV + c0;
    float wgts = wgt[s];
    uint2 u0 = *(const uint2*)&op[0];
    uint2 u1 = *(const uint2*)&op[4];
    uint2 u2 = *(const uint2*)&op[8];
    u32 uu[6] = {u0.x, u0.y, u1.x, u1.y, u2.x, u2.y};
#pragma unroll
    for (int j = 0; j < 6; ++j) {
      o[j * 2 + 0] = fmaf(wgts, bf2f((u16)(uu[j] & 0xFFFF)), o[j * 2 + 0]);
      o[j * 2 + 1] = fmaf(wgts, bf2f((u16)(uu[j] >> 16)), o[j * 2 + 1]);
    }
  }
  float inv = 1.0f / lsum;
  union { u16 hx[12]; uint2 v2[3]; } pk;
#pragma unroll
  for (int j = 0; j < 12; ++j) pk.hx[j] = f2bf(o[j] * inv);
  u16* dst = aout + (size_t)row * CC + h * VV + c0;
  *(uint2*)&dst[0] = pk.v2[0];
  *(uint2*)&dst[4] = pk.v2[1];
  *(uint2*)&dst[8] = pk.v2[2];
}

extern "C" void kernel_launch(void* const* d_in, const int* in_sizes, int n_in,
                              void* d_out, int out_size, void* d_ws, size_t ws_size,
                              hipStream_t stream) {
  (void)in_sizes; (void)n_in; (void)out_size; (void)ws_size;
  const float* x   = (const float*)d_in[0];
  const float* Wq  = (const float*)d_in[1];
  const float* Wk  = (const float*)d_in[2];
  const float* Wv  = (const float*)d_in[3];
  const float* Wr  = (const float*)d_in[4];
  const float* rwb = (const float*)d_in[5];
  const float* rrb = (const float*)d_in[6];
  const float* Wo  = (const float*)d_in[7];
  const float* bo  = (const float*)d_in[8];

  char* ws = (char*)d_ws;
  size_t off = 0;
  auto alloc = [&](size_t bytes) -> void* {
    void* p = ws + off;
    off += (bytes + 255) & ~(size_t)255;
    return p;
  };
  u16* WqT  = (u16*)alloc((size_t)512 * 1536 * 2);
  u16* WkT  = (u16*)alloc((size_t)512 * 1536 * 2);
  u16* WvT  = (u16*)alloc((size_t)1536 * 1536 * 2);
  u16* WoT  = (u16*)alloc((size_t)1536 * 1536 * 2);
  u16* xbf  = (u16*)alloc((size_t)TT * CC * 2);
  u16* qw   = (u16*)alloc((size_t)HH * TT * 64 * 2);
  u16* Kws  = (u16*)alloc((size_t)HH * TT * 64 * 2);
  u16* vTw  = (u16*)alloc((size_t)HH * VV * TT * 2);
  u16* aout = (u16*)alloc((size_t)TT * CC * 2);
  unsigned char* cidx_g = (unsigned char*)alloc(TT);
  u16* WrT      = (u16*)alloc((size_t)HH * 32 * 64 * 2);
  float* dW     = (float*)alloc((size_t)HH * 32 * 4);
  u16* o_part   = (u16*)alloc((size_t)SPLITS * HH * TT * VV * 2);
  float* m_part = (float*)alloc((size_t)SPLITS * HH * TT * 4);
  float* l_part = (float*)alloc((size_t)SPLITS * HH * TT * 4);

  prep_kernel<<<dim3(24, 24, 6), 256, 0, stream>>>(
      Wq, Wk, Wv, Wo, x, Wr, rwb, rrb,
      WqT, WkT, WvT, WoT, xbf, cidx_g, WrT, dW);
  gemm_qkv<<<dim3(20, 16), 256, 0, stream>>>(xbf, WqT, WkT, WvT,
                                             qw, Kws, vTw, rwb);
  attn_split<<<dim3(768), 256, 0, stream>>>(qw, Kws, vTw, WrT, dW, cidx_g,
                                            o_part, m_part, l_part);
  attn_combine<<<dim3(128, 8), 256, 0, stream>>>(o_part, m_part, l_part, aout);
  gemm_out<<<dim3(12, 16), 256, 0, stream>>>(aout, WoT, (float*)d_out, bo);
}